// Round 4
// baseline (2606.697 us; speedup 1.0000x reference)
//
#include <hip/hip_runtime.h>
#include <math.h>

#define EMBED 128
#define NCLS 21
#define NI_ 300
#define IMH 96
#define IMW 320
#define NPIX (IMH*IMW)
#define NQ 262144
#define NF_MAX 73728
#define INST_MAX 16
#define IH_MAX 64
#define RS32 0.17677669529663687f

// ---- SMALL region layout (4-byte units at ws base) ----
#define S_NF 0
#define S_NK 1
#define S_NINST 2
#define S_NIH 3
#define S_INVK 8      // 9 f
#define S_INVE 24     // 16 f
#define S_KIDX 64     // 300 i
#define S_SKK 400     // 300 f
#define S_MAREA 768   // 300 i
#define S_PAREA 1088  // 300 i
#define S_AREA2 1408  // 300 i
#define S_XYZ 1728    // 900 f
#define S_SELJ 2656   // 16 i
#define S_K2 2688     // 16 i
#define S_FCNT 3072   // 256 i
#define S_FOFF 3328   // 256 i
#define S_INSTQ 4096  // 16*128 f
#define S_INSTP 6144
#define S_QIN 8192
#define S_QH 10240
#define S_XI 12288
#define S_KHB 16384
#define S_VHB 18432
#define S_QKT 20480   // 64*128 f
#define S_SB 28672    // 64 f
#define S_SUMV 28928  // 64 f
#define S_WSUM 29056  // 64*128 f

#define OFF_FIDX ((size_t)1<<20)
#define OFF_INV  ((size_t)2<<20)
#define OFF_W1T  ((size_t)3<<20)
#define OFF_W2T  (((size_t)3<<20) + 512*128*4)
#define OFF_SE   ((size_t)4<<20)
#define SE_BYTES ((size_t)NF_MAX*128*4)
#define OFF_A1   (OFF_SE + SE_BYTES)
#define OFF_A2   (OFF_A1 + SE_BYTES)
#define OFF_SC   (OFF_A2 + SE_BYTES)

__global__ __launch_bounds__(256) void k_init(const float* Km, const float* Em, float* ws){
  int* iw = (int*)ws;
  for (int i = threadIdx.x; i < 4096; i += 256) iw[i] = 0;
  __syncthreads();
  if (threadIdx.x == 0){
    float* fw = ws;
    const float* K = Km;
    float A = K[4]*K[8]-K[5]*K[7];
    float B = K[5]*K[6]-K[3]*K[8];
    float C = K[3]*K[7]-K[4]*K[6];
    float det = K[0]*A + K[1]*B + K[2]*C;
    float id = 1.0f/det;
    fw[S_INVK+0] = A*id;
    fw[S_INVK+1] = (K[2]*K[7]-K[1]*K[8])*id;
    fw[S_INVK+2] = (K[1]*K[5]-K[2]*K[4])*id;
    fw[S_INVK+3] = B*id;
    fw[S_INVK+4] = (K[0]*K[8]-K[2]*K[6])*id;
    fw[S_INVK+5] = (K[2]*K[3]-K[0]*K[5])*id;
    fw[S_INVK+6] = C*id;
    fw[S_INVK+7] = (K[1]*K[6]-K[0]*K[7])*id;
    fw[S_INVK+8] = (K[0]*K[4]-K[1]*K[3])*id;
    // 4x4 Gauss-Jordan inverse of E
    float M[4][8];
    for (int r=0;r<4;r++){ for(int c=0;c<4;c++){ M[r][c]=Em[r*4+c]; M[r][4+c]=(r==c)?1.f:0.f; } }
    for (int col=0; col<4; col++){
      int piv=col; float best=fabsf(M[col][col]);
      for (int r=col+1;r<4;r++){ float v=fabsf(M[r][col]); if(v>best){best=v;piv=r;} }
      if (piv!=col){ for(int c=0;c<8;c++){ float tmp=M[col][c]; M[col][c]=M[piv][c]; M[piv][c]=tmp; } }
      float inv=1.0f/M[col][col];
      for (int c=0;c<8;c++) M[col][c]*=inv;
      for (int r=0;r<4;r++){ if(r==col) continue; float f=M[r][col]; for(int c=0;c<8;c++) M[r][c]-=f*M[col][c]; }
    }
    for (int r=0;r<4;r++) for(int c=0;c<4;c++) fw[S_INVE+r*4+c]=M[r][4+c];
  }
}

__global__ __launch_bounds__(320) void k_score(const float* logits, float* ws){
  int* iw=(int*)ws; float* fw=ws;
  __shared__ float ssc[NI_];
  __shared__ int skp[NI_];
  int t=threadIdx.x;
  if (t < NI_){
    float v[NCLS]; float mx=-1e30f;
    for (int c=0;c<NCLS;c++){
      float l=logits[t*NCLS+c];
      float sg=1.0f/(1.0f+expf(-l));
      float x=sg/0.06f;
      v[c]=x; mx=fmaxf(mx,x);
    }
    float s=0.f;
    for (int c=0;c<NCLS;c++) s += expf(v[c]-mx);
    float score=1.0f/s;     // max softmax prob
    ssc[t]=score; skp[t]=(score>0.25f)?1:0;
  }
  __syncthreads();
  if (t==0){
    int nk=0;
    for (int i=0;i<NI_;i++){ if(skp[i]){ iw[S_KIDX+nk]=i; fw[S_SKK+nk]=ssc[i]; nk++; } }
    iw[S_NK]=nk;
  }
}

// Block-level pre-reduction: per-query partial counts/sums in LDS, then
// at most nk*6 global atomics per block.
__global__ __launch_bounds__(256) void k_winner(const float* pmask, const float* depth, float* ws){
  int* iw=(int*)ws; float* fw=ws;
  int nk=iw[S_NK];
  if (nk>NI_) nk=NI_;
  __shared__ int s_pa[NI_], s_ma[NI_], s_a2[NI_];
  __shared__ float s_x[NI_], s_y[NI_], s_z[NI_];
  __shared__ int s_gi[NI_];
  __shared__ float s_sc[NI_];
  int t=threadIdx.x;
  int lane=t&63;
  for (int j=t;j<nk;j+=256){
    s_pa[j]=0; s_ma[j]=0; s_a2[j]=0;
    s_x[j]=0.f; s_y[j]=0.f; s_z[j]=0.f;
    s_gi[j]=iw[S_KIDX+j]; s_sc[j]=fw[S_SKK+j];
  }
  __syncthreads();
  int p=blockIdx.x*256+t;
  float best=-1e30f; int jw=-1; float mw=0.f;
  for (int j=0;j<nk;j++){
    float m=1.0f/(1.0f+expf(-pmask[(size_t)s_gi[j]*NPIX+p]));
    unsigned long long msk=__ballot(m>=0.5f);
    if (lane==0 && msk) atomicAdd(&s_pa[j], __popcll(msk));
    float wv=s_sc[j]*m;
    if (wv>best){ best=wv; jw=j; mw=m; }
  }
  if (jw>=0){
    atomicAdd(&s_ma[jw],1);
    if (mw>=0.5f){
      atomicAdd(&s_a2[jw],1);
      float d=depth[p];
      float gx=(float)(p%IMW)*4.0f, gy=(float)(p/IMW)*4.0f;
      float X=gx*d, Y=gy*d;
      const float* iK=fw+S_INVK; const float* iE=fw+S_INVE;
      float c0=iK[0]*X+iK[1]*Y+iK[2]*d;
      float c1=iK[3]*X+iK[4]*Y+iK[5]*d;
      float c2=iK[6]*X+iK[7]*Y+iK[8]*d;
      float wx=iE[0]*c0+iE[1]*c1+iE[2]*c2+iE[3];
      float wy=iE[4]*c0+iE[5]*c1+iE[6]*c2+iE[7];
      float wz=iE[8]*c0+iE[9]*c1+iE[10]*c2+iE[11];
      atomicAdd(&s_x[jw],wx);
      atomicAdd(&s_y[jw],wy);
      atomicAdd(&s_z[jw],wz);
    }
  }
  __syncthreads();
  for (int j=t;j<nk;j+=256){
    if (s_pa[j]) atomicAdd(&iw[S_PAREA+j],s_pa[j]);
    if (s_ma[j]) atomicAdd(&iw[S_MAREA+j],s_ma[j]);
    if (s_a2[j]) atomicAdd(&iw[S_AREA2+j],s_a2[j]);
    if (s_x[j]!=0.f) atomicAdd(&fw[S_XYZ+j*3+0],s_x[j]);
    if (s_y[j]!=0.f) atomicAdd(&fw[S_XYZ+j*3+1],s_y[j]);
    if (s_z[j]!=0.f) atomicAdd(&fw[S_XYZ+j*3+2],s_z[j]);
  }
}

__global__ __launch_bounds__(256) void k_sel(const float* queries, const float* instposw, const float* posw, float* ws){
  int* iw=(int*)ws; float* fw=ws;
  __shared__ int sn;
  if (threadIdx.x==0){
    int nk=iw[S_NK]; int n=0;
    for (int j=0;j<nk;j++){
      int a2=iw[S_AREA2+j];
      if (a2>0){
        float r=(float)iw[S_MAREA+j]/(float)iw[S_PAREA+j];
        if (r>=0.8f && n<INST_MAX){ iw[S_SELJ+n]=j; iw[S_K2+n]=iw[S_KIDX+j]; n++; }
      }
    }
    iw[S_NINST]=n; iw[S_NIH]=4*n; sn=n;
  }
  __syncthreads();
  int n=sn;
  for (int idx=threadIdx.x; idx<n*128; idx+=256){
    int i=idx>>7, e=idx&127;
    int j=iw[S_SELJ+i]; int gi=iw[S_K2+i];
    fw[S_INSTQ+idx]=queries[gi*128+e];
    float mp=fw[S_XYZ+j*3]*posw[e*3]+fw[S_XYZ+j*3+1]*posw[e*3+1]+fw[S_XYZ+j*3+2]*posw[e*3+2];
    fw[S_INSTP+idx]=instposw[gi*128+e]+mp;
  }
}

__global__ __launch_bounds__(256) void k_fov_count(const int* fov, float* ws){
  int* iw=(int*)ws;
  __shared__ int red[256];
  int t=threadIdx.x;
  int base=blockIdx.x*1024;
  int s=0;
  for (int k=0;k<4;k++) s += (fov[base+k*256+t]!=0)?1:0;
  red[t]=s; __syncthreads();
  for (int st=128;st>0;st>>=1){ if(t<st) red[t]+=red[t+st]; __syncthreads(); }
  if (t==0) iw[S_FCNT+blockIdx.x]=red[0];
}

__global__ void k_fov_scan(float* ws){
  int* iw=(int*)ws;
  if (threadIdx.x==0){
    int acc=0;
    for (int b=0;b<256;b++){ iw[S_FOFF+b]=acc; acc+=iw[S_FCNT+b]; }
    iw[S_NF]=(acc<NF_MAX)?acc:NF_MAX;
  }
}

__global__ __launch_bounds__(256) void k_fov_scatter(const int* fov, float* ws){
  int* iw=(int*)ws;
  int* fidx=(int*)((char*)ws+OFF_FIDX);
  int* invr=(int*)((char*)ws+OFF_INV);
  __shared__ int wsums[4];
  __shared__ int woff[4];
  __shared__ int cur;
  __shared__ int tot;
  int t=threadIdx.x; int w=t>>6; int lane=t&63;
  if (t==0) cur=iw[S_FOFF+blockIdx.x];
  __syncthreads();
  int base=blockIdx.x*1024;
  for (int k=0;k<4;k++){
    int i=base+k*256+t;
    int f=(fov[i]!=0)?1:0;
    unsigned long long m=__ballot(f);
    int rk=__popcll(m & ((lane==0)?0ull:((~0ull)>>(64-lane))));
    if (lane==0) wsums[w]=__popcll(m);
    __syncthreads();
    if (t==0){ int a=0; for(int q2=0;q2<4;q2++){ woff[q2]=a; a+=wsums[q2]; } tot=a; }
    __syncthreads();
    if (f){
      int r=cur+woff[w]+rk;
      if (r<NF_MAX){ fidx[r]=i; invr[i]=r; } else invr[i]=-1;
    } else invr[i]=-1;
    __syncthreads();
    if (t==0) cur+=tot;
    __syncthreads();
  }
}

__global__ __launch_bounds__(256) void k_se_build(const float* sew, const float* x3d, const int* fidx, float* SE, float* ws){
  int* iw=(int*)ws;
  int nf=iw[S_NF];
  int r0=blockIdx.x*64;
  if (r0>=nf) return;
  int nr=min(64,nf-r0);
  __shared__ float tile[64][129];
  __shared__ int fidxl[64];
  int t=threadIdx.x;
  if (t<64) fidxl[t]=(t<nr)? fidx[r0+t]:0;
  __syncthreads();
  for (int idx=t; idx<64*128; idx+=256){
    int v=idx>>7, e=idx&127;
    tile[v][e]=(v<nr)? sew[(size_t)fidxl[v]*128+e]:0.f;
  }
  __syncthreads();
  for (int idx=t; idx<128*64; idx+=256){
    int c=idx>>6, v=idx&63;
    if (v<nr) tile[v][c]+=x3d[(size_t)c*NQ+fidxl[v]];
  }
  __syncthreads();
  for (int idx=t; idx<64*128; idx+=256){
    int v=idx>>7, e=idx&127;
    if (v<nr) SE[(r0+v)*128+e]=tile[v][e];
  }
}

__global__ __launch_bounds__(256) void kA_prep(const float* Wq, const float* bq, const float* Wk, const float* bk, float* ws){
  int* iw=(int*)ws; float* fw=ws;
  int n=iw[S_NINST]; int nih=iw[S_NIH];
  int t=threadIdx.x;
  for (int idx=t; idx<n*128; idx+=256) fw[S_QIN+idx]=fw[S_INSTQ+idx]+fw[S_INSTP+idx];
  __syncthreads();
  for (int idx=t; idx<n*128; idx+=256){
    int i=idx>>7, e=idx&127;
    float a=bq[e];
    for (int k=0;k<128;k++) a+=fw[S_QIN+i*128+k]*Wq[e*128+k];
    fw[S_QH+idx]=a;
  }
  __syncthreads();
  for (int idx=t; idx<nih*128; idx+=256){
    int ih=idx>>7, e=idx&127;
    int i=ih>>2, h=ih&3;
    float a=0.f;
    for (int d=0;d<32;d++) a+=fw[S_QH+i*128+h*32+d]*Wk[(h*32+d)*128+e];
    fw[S_QKT+idx]=a*RS32;
  }
  for (int ih=t; ih<nih; ih+=256){
    int i=ih>>2, h=ih&3;
    float a=0.f;
    for (int d=0;d<32;d++) a+=fw[S_QH+i*128+h*32+d]*bk[h*32+d];
    fw[S_SB+ih]=a*RS32;
  }
}

__global__ __launch_bounds__(256) void kS1(const float* SE, float* SC, const float* posw, const float* org, const int* fidx, float* ws){
  int* iw=(int*)ws; float* fw=ws;
  int nf=iw[S_NF]; int nih=iw[S_NIH];
  int r0=blockIdx.x*64;
  if (r0>=nf || nih==0) return;
  int nr=min(64,nf-r0);
  __shared__ float xt[64][129];
  __shared__ float qk[IH_MAX*128];
  __shared__ float sbl[IH_MAX];
  __shared__ float pwl[384];
  __shared__ float px[64],py[64],pz[64];
  __shared__ int fidxl[64];
  int t=threadIdx.x;
  for (int i=t;i<384;i+=256) pwl[i]=posw[i];
  if (t<64) fidxl[t]=(t<nr)? fidx[r0+t]:0;
  for (int idx=t; idx<nih*128; idx+=256) qk[idx]=fw[S_QKT+idx];
  if (t<IH_MAX) sbl[t]=(t<nih)? fw[S_SB+t]:0.f;
  __syncthreads();
  if (t<64){
    int q=fidxl[t];
    int vx=q>>11, vy=(q>>4)&127, vz=q&15;
    px[t]=(vx+0.5f)*0.2f+org[0];
    py[t]=(vy+0.5f)*0.2f+org[1];
    pz[t]=(vz+0.5f)*0.2f+org[2];
  }
  __syncthreads();
  for (int idx=t; idx<64*128; idx+=256){
    int v=idx>>7, e=idx&127;
    float val=0.f;
    if (v<nr) val=SE[(r0+v)*128+e]+px[v]*pwl[e*3]+py[v]*pwl[e*3+1]+pz[v]*pwl[e*3+2];
    xt[v][e]=val;
  }
  __syncthreads();
  int tokl=t&63, base=t>>6;
  for (int ih=base; ih<nih; ih+=4){
    float a=sbl[ih];
    const float* qrow=qk+ih*128;
    for (int e=0;e<128;e++) a+=qrow[e]*xt[tokl][e];
    if (tokl<nr) SC[(size_t)ih*NF_MAX+r0+tokl]=a;
  }
}

__global__ __launch_bounds__(256) void kS2S3(float* SC, float* ws){
  int* iw=(int*)ws; float* fw=ws;
  int nih=iw[S_NIH]; int ih=blockIdx.x;
  if (ih>=nih) return;
  int nf=iw[S_NF];
  float* row=SC+(size_t)ih*NF_MAX;
  __shared__ float red[256];
  int t=threadIdx.x;
  float m=-1e30f;
  for (int j=t;j<nf;j+=256) m=fmaxf(m,row[j]);
  red[t]=m; __syncthreads();
  for (int s=128;s>0;s>>=1){ if(t<s) red[t]=fmaxf(red[t],red[t+s]); __syncthreads(); }
  m=red[0]; __syncthreads();
  float sum=0.f;
  for (int j=t;j<nf;j+=256){ float p=expf(row[j]-m); row[j]=p; sum+=p; }
  red[t]=sum; __syncthreads();
  for (int s=128;s>0;s>>=1){ if(t<s) red[t]+=red[t+s]; __syncthreads(); }
  if (t==0) fw[S_SUMV+ih]=red[0];
  if (t<128) fw[S_WSUM+ih*128+t]=0.f;
}

__global__ __launch_bounds__(256) void kS4(const float* SC, const float* SE, float* ws){
  int* iw=(int*)ws; float* fw=ws;
  int nf=iw[S_NF]; int nih=iw[S_NIH];
  if (nih==0) return;
  int t=threadIdx.x;
  int chunk=(nf+255)/256;
  int j0=blockIdx.x*chunk;
  int j1=min(nf,j0+chunk);
  if (j0>=j1) return;
  __shared__ float pt[64*64];
  int e=t&127, half=t>>7;
  float acc[32];
  #pragma unroll
  for (int r=0;r<32;r++) acc[r]=0.f;
  for (int jj=j0; jj<j1; jj+=64){
    int cnt=min(64,j1-jj);
    __syncthreads();
    for (int idx=t; idx<64*64; idx+=256){
      int ih=idx>>6, jl=idx&63;
      pt[idx]=(ih<nih && jl<cnt)? SC[(size_t)ih*NF_MAX+jj+jl]:0.f;
    }
    __syncthreads();
    for (int jl=0; jl<cnt; jl++){
      float sv=SE[(jj+jl)*128+e];
      #pragma unroll
      for (int r=0;r<32;r++) acc[r]+=pt[(half*32+r)*64+jl]*sv;
    }
  }
  #pragma unroll
  for (int r=0;r<32;r++) atomicAdd(&fw[S_WSUM+(half*32+r)*128+e], acc[r]);
}

__global__ __launch_bounds__(256) void kA_post(const float* Wv, const float* bv, const float* Wo, const float* bo,
    const float* g, const float* bb, float* ws){
  int* iw=(int*)ws; float* fw=ws;
  int n=iw[S_NINST]; int nih=iw[S_NIH];
  __shared__ float wn[IH_MAX*128];
  __shared__ float ol[INST_MAX*128];
  __shared__ float tl[INST_MAX*128];
  int t=threadIdx.x;
  for (int idx=t; idx<nih*128; idx+=256){
    int ih=idx>>7;
    wn[idx]=fw[S_WSUM+idx]/fw[S_SUMV+ih];
  }
  __syncthreads();
  for (int idx=t; idx<n*128; idx+=256){
    int i=idx>>7, f=idx&127; int h=f>>5;
    float a=bv[f];
    const float* wrow=Wv+f*128;
    const float* wv=wn+(i*4+h)*128;
    for (int e2=0;e2<128;e2++) a+=wrow[e2]*wv[e2];
    ol[idx]=a;
  }
  __syncthreads();
  for (int idx=t; idx<n*128; idx+=256){
    int i=idx>>7, e2=idx&127;
    float a=bo[e2];
    const float* orow=ol+i*128;
    const float* wrow=Wo+e2*128;
    for (int f2=0;f2<128;f2++) a+=orow[f2]*wrow[f2];
    tl[idx]=a+fw[S_QIN+idx];
  }
  __syncthreads();
  int w=t>>6, lane=t&63;
  for (int i=w;i<n;i+=4){
    float v0=tl[i*128+lane], v1=tl[i*128+64+lane];
    float s=v0+v1;
    for (int o=32;o>0;o>>=1) s+=__shfl_xor(s,o);
    float mu=s*(1.f/128.f);
    float d0=v0-mu, d1=v1-mu;
    float vv=d0*d0+d1*d1;
    for (int o=32;o>0;o>>=1) vv+=__shfl_xor(vv,o);
    float rsv=rsqrtf(vv*(1.f/128.f)+1e-5f);
    fw[S_XI+i*128+lane]=d0*rsv*g[lane]+bb[lane];
    fw[S_XI+i*128+64+lane]=d1*rsv*g[64+lane]+bb[64+lane];
  }
}

__global__ __launch_bounds__(256) void kA_ffn(const float* W1, const float* b1, const float* W2, const float* b2,
    const float* g, const float* bb, float* ws){
  int* iw=(int*)ws; float* fw=ws;
  int n=iw[S_NINST];
  int i=blockIdx.x;
  if (i>=n) return;
  __shared__ float xl[128];
  __shared__ float hid[512];
  __shared__ float yv[128];
  int t=threadIdx.x;
  if (t<128) xl[t]=fw[S_XI+i*128+t];
  __syncthreads();
  for (int d=t; d<512; d+=256){
    float a=b1[d];
    const float* wr=W1+d*128;
    for (int k=0;k<128;k++) a+=wr[k]*xl[k];
    hid[d]=fmaxf(a,0.f);
  }
  __syncthreads();
  if (t<128){
    float a=b2[t];
    const float* wr=W2+(size_t)t*512;
    for (int d=0;d<512;d++) a+=wr[d]*hid[d];
    yv[t]=a+xl[t];
  }
  __syncthreads();
  if (t<64){
    float v0=yv[t], v1=yv[t+64];
    float s=v0+v1;
    for (int o=32;o>0;o>>=1) s+=__shfl_xor(s,o);
    float mu=s*(1.f/128.f);
    float d0=v0-mu, d1=v1-mu;
    float vv=d0*d0+d1*d1;
    for (int o=32;o>0;o>>=1) vv+=__shfl_xor(vv,o);
    float rsv=rsqrtf(vv*(1.f/128.f)+1e-5f);
    fw[S_INSTQ+i*128+t]=d0*rsv*g[t]+bb[t];
    fw[S_INSTQ+i*128+64+t]=d1*rsv*g[64+t]+bb[64+t];
  }
}

__global__ __launch_bounds__(256) void kA_kv(const float* Wk2, const float* bk2, const float* Wv2, const float* bv2, float* ws){
  int* iw=(int*)ws; float* fw=ws;
  int n=iw[S_NINST];
  int t=threadIdx.x;
  for (int idx=t; idx<n*128; idx+=256){
    int i=idx>>7, e=idx&127;
    float ak=bk2[e], av=bv2[e];
    const float* wk=Wk2+e*128;
    const float* wv=Wv2+e*128;
    for (int k=0;k<128;k++){
      float qv=fw[S_INSTQ+i*128+k];
      float qp=qv+fw[S_INSTP+i*128+k];
      ak+=qp*wk[k];
      av+=qv*wv[k];
    }
    fw[S_KHB+idx]=ak; fw[S_VHB+idx]=av;
  }
}

// kQ: scene-side q-projection. A1[r][e] = (SE[r]+pos(r)) . Wq[e][:] + bq[e].
// Pos-augmented input staged ONCE to LDS (stride 132, b128-aligned); GEMM is
// 4x8 register-tiled: A via broadcast ds_read_b128 (16 lanes same addr,
// conflict-free), W direct from global (L1-resident, 64KB). No Wsh staging.
__global__ __launch_bounds__(256) void kQ(float* __restrict__ A1,
    const float* __restrict__ Wq, const float* __restrict__ bq,
    const float* __restrict__ SE, const int* __restrict__ fidx,
    const float* __restrict__ posw, const float* __restrict__ org, float* __restrict__ ws){
  int* iw=(int*)ws;
  int nf=iw[S_NF];
  int r0=blockIdx.x*64;
  if (r0>=nf) return;
  __shared__ float Xs[64][132];
  __shared__ float pwl[384];
  __shared__ float px[64],py[64],pz[64];
  int t=threadIdx.x;
  for (int i=t;i<384;i+=256) pwl[i]=posw[i];
  if (t<64){
    int r=r0+t;
    int q=(r<nf)? fidx[r]:0;
    int vx=q>>11, vy=(q>>4)&127, vz=q&15;
    px[t]=(vx+0.5f)*0.2f+org[0];
    py[t]=(vy+0.5f)*0.2f+org[1];
    pz[t]=(vz+0.5f)*0.2f+org[2];
  }
  __syncthreads();
  for (int idx=t; idx<64*32; idx+=256){
    int rl=idx>>5, e4=(idx&31)*4;
    float4 v=*reinterpret_cast<const float4*>(SE+(size_t)(r0+rl)*128+e4);
    float X=px[rl], Y=py[rl], Z=pz[rl];
    v.x+=X*pwl[(e4+0)*3]+Y*pwl[(e4+0)*3+1]+Z*pwl[(e4+0)*3+2];
    v.y+=X*pwl[(e4+1)*3]+Y*pwl[(e4+1)*3+1]+Z*pwl[(e4+1)*3+2];
    v.z+=X*pwl[(e4+2)*3]+Y*pwl[(e4+2)*3+1]+Z*pwl[(e4+2)*3+2];
    v.w+=X*pwl[(e4+3)*3]+Y*pwl[(e4+3)*3+1]+Z*pwl[(e4+3)*3+2];
    *reinterpret_cast<float4*>(&Xs[rl][e4])=v;
  }
  __syncthreads();
  int tx=t&15, ty=t>>4, ty4=ty*4, ecol=tx*8;
  float acc[4][8];
  #pragma unroll
  for (int i=0;i<4;i++)
    #pragma unroll
    for (int j=0;j<8;j++) acc[i][j]=0.f;
  for (int k=0;k<128;k+=4){
    float4 xv0=*reinterpret_cast<const float4*>(&Xs[ty4+0][k]);
    float4 xv1=*reinterpret_cast<const float4*>(&Xs[ty4+1][k]);
    float4 xv2=*reinterpret_cast<const float4*>(&Xs[ty4+2][k]);
    float4 xv3=*reinterpret_cast<const float4*>(&Xs[ty4+3][k]);
    #pragma unroll
    for (int jj=0;jj<8;jj++){
      float4 w=*reinterpret_cast<const float4*>(Wq+(size_t)(ecol+jj)*128+k);
      acc[0][jj]+=xv0.x*w.x+xv0.y*w.y+xv0.z*w.z+xv0.w*w.w;
      acc[1][jj]+=xv1.x*w.x+xv1.y*w.y+xv1.z*w.z+xv1.w*w.w;
      acc[2][jj]+=xv2.x*w.x+xv2.y*w.y+xv2.z*w.z+xv2.w*w.w;
      acc[3][jj]+=xv3.x*w.x+xv3.y*w.y+xv3.z*w.z+xv3.w*w.w;
    }
  }
  float4 bqa=*reinterpret_cast<const float4*>(bq+ecol);
  float4 bqb=*reinterpret_cast<const float4*>(bq+ecol+4);
  #pragma unroll
  for (int i=0;i<4;i++){
    int r=r0+ty4+i;
    if (r>=nf) continue;
    float4 o1, o2;
    o1.x=acc[i][0]+bqa.x; o1.y=acc[i][1]+bqa.y; o1.z=acc[i][2]+bqa.z; o1.w=acc[i][3]+bqa.w;
    o2.x=acc[i][4]+bqb.x; o2.y=acc[i][5]+bqb.y; o2.z=acc[i][6]+bqb.z; o2.w=acc[i][7]+bqb.w;
    *reinterpret_cast<float4*>(A1+(size_t)r*128+ecol)=o1;
    *reinterpret_cast<float4*>(A1+(size_t)r*128+ecol+4)=o2;
  }
}

// kAttnOLN: fuses kB2 (16-key attention) + o-projection + residual(SE+pos) +
// LayerNorm. Attention runs in-place on the staged A1 tile in LDS; o-proj is
// 4x8 register-tiled (A broadcast b128, Wo via L1); LN is in-register via
// 16-lane shfl_xor (each row's 128 cols live in one tx-group).
__global__ __launch_bounds__(256) void kAttnOLN(const float* __restrict__ A1, float* __restrict__ A2,
    const float* __restrict__ Wo, const float* __restrict__ bo,
    const float* __restrict__ g, const float* __restrict__ bb,
    const float* __restrict__ SE, const int* __restrict__ fidx,
    const float* __restrict__ posw, const float* __restrict__ org, float* __restrict__ ws){
  int* iw=(int*)ws; float* fw=ws;
  int nf=iw[S_NF]; int n=iw[S_NINST];
  int r0=blockIdx.x*64;
  if (r0>=nf) return;
  __shared__ float ot[64][132];
  __shared__ float kh[INST_MAX*128];
  __shared__ float vh[INST_MAX*128];
  __shared__ float pwl[384];
  __shared__ float px[64],py[64],pz[64];
  int t=threadIdx.x;
  for (int idx=t; idx<INST_MAX*128; idx+=256){
    kh[idx]=(idx<n*128)? fw[S_KHB+idx]:0.f;
    vh[idx]=(idx<n*128)? fw[S_VHB+idx]:0.f;
  }
  for (int i=t;i<384;i+=256) pwl[i]=posw[i];
  if (t<64){
    int r=r0+t;
    int q=(r<nf)? fidx[r]:0;
    int vx=q>>11, vy=(q>>4)&127, vz=q&15;
    px[t]=(vx+0.5f)*0.2f+org[0];
    py[t]=(vy+0.5f)*0.2f+org[1];
    pz[t]=(vz+0.5f)*0.2f+org[2];
  }
  for (int idx=t; idx<64*32; idx+=256){
    int rl=idx>>5, e4=(idx&31)*4;
    *reinterpret_cast<float4*>(&ot[rl][e4]) =
      *reinterpret_cast<const float4*>(A1+(size_t)(r0+rl)*128+e4);
  }
  __syncthreads();
  // attention: thread (tokl, h) owns cols h*32..h*32+31 of row tokl (exclusive)
  {
    int tokl=t&63, h=t>>6;
    float q[32];
    #pragma unroll
    for (int d8=0;d8<8;d8++){
      float4 v=*reinterpret_cast<const float4*>(&ot[tokl][h*32+d8*4]);
      q[d8*4]=v.x; q[d8*4+1]=v.y; q[d8*4+2]=v.z; q[d8*4+3]=v.w;
    }
    float s[INST_MAX]; float mx=-1e30f;
    for (int j=0;j<INST_MAX;j++){
      float a=0.f;
      #pragma unroll
      for (int d4=0;d4<8;d4++){
        float4 kv=*reinterpret_cast<const float4*>(&kh[j*128+h*32+d4*4]);
        a+=q[d4*4]*kv.x+q[d4*4+1]*kv.y+q[d4*4+2]*kv.z+q[d4*4+3]*kv.w;
      }
      a*=RS32;
      s[j]=(j<n)? a:-1e30f;
      mx=fmaxf(mx,s[j]);
    }
    float sum=0.f;
    for (int j=0;j<INST_MAX;j++){ float p=expf(s[j]-mx); s[j]=p; sum+=p; }
    float inv=(n>0)? 1.0f/sum:0.f;
    float o[32];
    #pragma unroll
    for (int d=0;d<32;d++) o[d]=0.f;
    for (int j=0;j<INST_MAX;j++){
      float a=s[j]*inv;
      #pragma unroll
      for (int d4=0;d4<8;d4++){
        float4 vv=*reinterpret_cast<const float4*>(&vh[j*128+h*32+d4*4]);
        o[d4*4]+=a*vv.x; o[d4*4+1]+=a*vv.y; o[d4*4+2]+=a*vv.z; o[d4*4+3]+=a*vv.w;
      }
    }
    #pragma unroll
    for (int d8=0;d8<8;d8++){
      float4 v; v.x=o[d8*4]; v.y=o[d8*4+1]; v.z=o[d8*4+2]; v.w=o[d8*4+3];
      *reinterpret_cast<float4*>(&ot[tokl][h*32+d8*4])=v;
    }
  }
  __syncthreads();
  // o-proj + residual + LN
  int tx=t&15, ty=t>>4, ty4=ty*4, ecol=tx*8;
  float acc[4][8];
  #pragma unroll
  for (int i=0;i<4;i++)
    #pragma unroll
    for (int j=0;j<8;j++) acc[i][j]=0.f;
  for (int k=0;k<128;k+=4){
    float4 xv0=*reinterpret_cast<const float4*>(&ot[ty4+0][k]);
    float4 xv1=*reinterpret_cast<const float4*>(&ot[ty4+1][k]);
    float4 xv2=*reinterpret_cast<const float4*>(&ot[ty4+2][k]);
    float4 xv3=*reinterpret_cast<const float4*>(&ot[ty4+3][k]);
    #pragma unroll
    for (int jj=0;jj<8;jj++){
      float4 w=*reinterpret_cast<const float4*>(Wo+(size_t)(ecol+jj)*128+k);
      acc[0][jj]+=xv0.x*w.x+xv0.y*w.y+xv0.z*w.z+xv0.w*w.w;
      acc[1][jj]+=xv1.x*w.x+xv1.y*w.y+xv1.z*w.z+xv1.w*w.w;
      acc[2][jj]+=xv2.x*w.x+xv2.y*w.y+xv2.z*w.z+xv2.w*w.w;
      acc[3][jj]+=xv3.x*w.x+xv3.y*w.y+xv3.z*w.z+xv3.w*w.w;
    }
  }
  float4 boa=*reinterpret_cast<const float4*>(bo+ecol);
  float4 bob=*reinterpret_cast<const float4*>(bo+ecol+4);
  float4 ga=*reinterpret_cast<const float4*>(g+ecol);
  float4 gb=*reinterpret_cast<const float4*>(g+ecol+4);
  float4 ba=*reinterpret_cast<const float4*>(bb+ecol);
  float4 bbv=*reinterpret_cast<const float4*>(bb+ecol+4);
  float pe[8][3];
  #pragma unroll
  for (int jj=0;jj<8;jj++){
    pe[jj][0]=pwl[(ecol+jj)*3]; pe[jj][1]=pwl[(ecol+jj)*3+1]; pe[jj][2]=pwl[(ecol+jj)*3+2];
  }
  #pragma unroll
  for (int i=0;i<4;i++){
    int r=r0+ty4+i;
    float4 se1=*reinterpret_cast<const float4*>(SE+(size_t)r*128+ecol);
    float4 se2=*reinterpret_cast<const float4*>(SE+(size_t)r*128+ecol+4);
    float X=px[ty4+i], Y=py[ty4+i], Z=pz[ty4+i];
    acc[i][0]+=boa.x+se1.x+X*pe[0][0]+Y*pe[0][1]+Z*pe[0][2];
    acc[i][1]+=boa.y+se1.y+X*pe[1][0]+Y*pe[1][1]+Z*pe[1][2];
    acc[i][2]+=boa.z+se1.z+X*pe[2][0]+Y*pe[2][1]+Z*pe[2][2];
    acc[i][3]+=boa.w+se1.w+X*pe[3][0]+Y*pe[3][1]+Z*pe[3][2];
    acc[i][4]+=bob.x+se2.x+X*pe[4][0]+Y*pe[4][1]+Z*pe[4][2];
    acc[i][5]+=bob.y+se2.y+X*pe[5][0]+Y*pe[5][1]+Z*pe[5][2];
    acc[i][6]+=bob.z+se2.z+X*pe[6][0]+Y*pe[6][1]+Z*pe[6][2];
    acc[i][7]+=bob.w+se2.w+X*pe[7][0]+Y*pe[7][1]+Z*pe[7][2];
    // LayerNorm across the 16 tx lanes of this row (128 cols total)
    float s1=0.f;
    #pragma unroll
    for (int jj=0;jj<8;jj++) s1+=acc[i][jj];
    s1+=__shfl_xor(s1,1); s1+=__shfl_xor(s1,2); s1+=__shfl_xor(s1,4); s1+=__shfl_xor(s1,8);
    float mu=s1*(1.f/128.f);
    float vv=0.f;
    #pragma unroll
    for (int jj=0;jj<8;jj++){ float d=acc[i][jj]-mu; acc[i][jj]=d; vv+=d*d; }
    vv+=__shfl_xor(vv,1); vv+=__shfl_xor(vv,2); vv+=__shfl_xor(vv,4); vv+=__shfl_xor(vv,8);
    float rsv=rsqrtf(vv*(1.f/128.f)+1e-5f);
    if (r<nf){
      float4 o1,o2;
      o1.x=acc[i][0]*rsv*ga.x+ba.x; o1.y=acc[i][1]*rsv*ga.y+ba.y;
      o1.z=acc[i][2]*rsv*ga.z+ba.z; o1.w=acc[i][3]*rsv*ga.w+ba.w;
      o2.x=acc[i][4]*rsv*gb.x+bbv.x; o2.y=acc[i][5]*rsv*gb.y+bbv.y;
      o2.z=acc[i][6]*rsv*gb.z+bbv.z; o2.w=acc[i][7]*rsv*gb.w+bbv.w;
      *reinterpret_cast<float4*>(A2+(size_t)r*128+ecol)=o1;
      *reinterpret_cast<float4*>(A2+(size_t)r*128+ecol+4)=o2;
    }
  }
}

__global__ void k_transpose(const float* in, float* outp, int R, int C){
  __shared__ float tile[32][33];
  int bx=blockIdx.x*32, by=blockIdx.y*32;
  int tx=threadIdx.x, ty=threadIdx.y;
  for (int k=0;k<4;k++){
    int r=by+ty+k*8, c=bx+tx;
    if (r<R && c<C) tile[ty+k*8][tx]=in[(size_t)r*C+c];
  }
  __syncthreads();
  for (int k=0;k<4;k++){
    int cc=bx+ty+k*8, rr=by+tx;
    if (rr<R && cc<C) outp[(size_t)cc*R+rr]=tile[tx][ty+k*8];
  }
}

// Fused FFN (v1, measured 357us): 64-row tile, register-tiled GEMM1 (4x4/thread)
// -> H chunk in LDS -> register-tiled GEMM2 (4x8/thread, persistent acc)
// -> residual+LN. Balance-bound across VALU/LDS/L1 pipes; pinned at v1.
__global__ __launch_bounds__(256) void kFFN(const float* X_, float* SEo, const float* W1T, const float* W2T,
    const float* b1, const float* b2, const float* g, const float* bb, float* ws){
  int* iw=(int*)ws;
  int nf=iw[S_NF];
  int r0=blockIdx.x*64;
  if (r0>=nf) return;
  __shared__ float Xs[64][132];
  __shared__ float Hs[64][68];
  int t=threadIdx.x;
  int tx=t&15, ty=t>>4;
  int ty4=ty*4;
  int ecol=tx*8;
  for (int idx=t; idx<64*32; idx+=256){
    int rl=idx>>5, e4=idx&31;
    int r=r0+rl;
    float4 v = (r<nf)? reinterpret_cast<const float4*>(X_+(size_t)r*128)[e4]
                     : make_float4(0.f,0.f,0.f,0.f);
    *reinterpret_cast<float4*>(&Xs[rl][e4*4]) = v;
  }
  __syncthreads();
  float yacc[4][8];
  #pragma unroll
  for (int i=0;i<4;i++)
    #pragma unroll
    for (int j=0;j<8;j++) yacc[i][j]=0.f;
  for (int dc=0; dc<512; dc+=64){
    int dcol = dc + tx*4;
    float acc[4][4];
    #pragma unroll
    for (int i=0;i<4;i++)
      #pragma unroll
      for (int j=0;j<4;j++) acc[i][j]=0.f;
    for (int k=0;k<128;k+=4){
      float4 w0=*reinterpret_cast<const float4*>(W1T+(size_t)(k+0)*512+dcol);
      float4 w1=*reinterpret_cast<const float4*>(W1T+(size_t)(k+1)*512+dcol);
      float4 w2=*reinterpret_cast<const float4*>(W1T+(size_t)(k+2)*512+dcol);
      float4 w3=*reinterpret_cast<const float4*>(W1T+(size_t)(k+3)*512+dcol);
      #pragma unroll
      for (int i=0;i<4;i++){
        float4 xv=*reinterpret_cast<const float4*>(&Xs[ty4+i][k]);
        acc[i][0]+=xv.x*w0.x; acc[i][1]+=xv.x*w0.y; acc[i][2]+=xv.x*w0.z; acc[i][3]+=xv.x*w0.w;
        acc[i][0]+=xv.y*w1.x; acc[i][1]+=xv.y*w1.y; acc[i][2]+=xv.y*w1.z; acc[i][3]+=xv.y*w1.w;
        acc[i][0]+=xv.z*w2.x; acc[i][1]+=xv.z*w2.y; acc[i][2]+=xv.z*w2.z; acc[i][3]+=xv.z*w2.w;
        acc[i][0]+=xv.w*w3.x; acc[i][1]+=xv.w*w3.y; acc[i][2]+=xv.w*w3.z; acc[i][3]+=xv.w*w3.w;
      }
    }
    float4 b1v=*reinterpret_cast<const float4*>(b1+dcol);
    #pragma unroll
    for (int i=0;i<4;i++){
      float4 h;
      h.x=fmaxf(acc[i][0]+b1v.x,0.f);
      h.y=fmaxf(acc[i][1]+b1v.y,0.f);
      h.z=fmaxf(acc[i][2]+b1v.z,0.f);
      h.w=fmaxf(acc[i][3]+b1v.w,0.f);
      *reinterpret_cast<float4*>(&Hs[ty4+i][tx*4])=h;
    }
    __syncthreads();
    for (int d=0; d<64; d+=4){
      float4 ha0=*reinterpret_cast<const float4*>(&Hs[ty4+0][d]);
      float4 ha1=*reinterpret_cast<const float4*>(&Hs[ty4+1][d]);
      float4 ha2=*reinterpret_cast<const float4*>(&Hs[ty4+2][d]);
      float4 ha3=*reinterpret_cast<const float4*>(&Hs[ty4+3][d]);
      #pragma unroll
      for (int kk=0;kk<4;kk++){
        const float* wrow=W2T+(size_t)(dc+d+kk)*128+ecol;
        float4 wa=*reinterpret_cast<const float4*>(wrow);
        float4 wb=*reinterpret_cast<const float4*>(wrow+4);
        float h0 = (kk==0)?ha0.x:(kk==1)?ha0.y:(kk==2)?ha0.z:ha0.w;
        float h1 = (kk==0)?ha1.x:(kk==1)?ha1.y:(kk==2)?ha1.z:ha1.w;
        float h2 = (kk==0)?ha2.x:(kk==1)?ha2.y:(kk==2)?ha2.z:ha2.w;
        float h3 = (kk==0)?ha3.x:(kk==1)?ha3.y:(kk==2)?ha3.z:ha3.w;
        yacc[0][0]+=h0*wa.x; yacc[0][1]+=h0*wa.y; yacc[0][2]+=h0*wa.z; yacc[0][3]+=h0*wa.w;
        yacc[0][4]+=h0*wb.x; yacc[0][5]+=h0*wb.y; yacc[0][6]+=h0*wb.z; yacc[0][7]+=h0*wb.w;
        yacc[1][0]+=h1*wa.x; yacc[1][1]+=h1*wa.y; yacc[1][2]+=h1*wa.z; yacc[1][3]+=h1*wa.w;
        yacc[1][4]+=h1*wb.x; yacc[1][5]+=h1*wb.y; yacc[1][6]+=h1*wb.z; yacc[1][7]+=h1*wb.w;
        yacc[2][0]+=h2*wa.x; yacc[2][1]+=h2*wa.y; yacc[2][2]+=h2*wa.z; yacc[2][3]+=h2*wa.w;
        yacc[2][4]+=h2*wb.x; yacc[2][5]+=h2*wb.y; yacc[2][6]+=h2*wb.z; yacc[2][7]+=h2*wb.w;
        yacc[3][0]+=h3*wa.x; yacc[3][1]+=h3*wa.y; yacc[3][2]+=h3*wa.z; yacc[3][3]+=h3*wa.w;
        yacc[3][4]+=h3*wb.x; yacc[3][5]+=h3*wb.y; yacc[3][6]+=h3*wb.z; yacc[3][7]+=h3*wb.w;
      }
    }
    __syncthreads();
  }
  float4 b2a=*reinterpret_cast<const float4*>(b2+ecol);
  float4 b2b=*reinterpret_cast<const float4*>(b2+ecol+4);
  #pragma unroll
  for (int i=0;i<4;i++){
    float4 xa=*reinterpret_cast<const float4*>(&Xs[ty4+i][ecol]);
    float4 xb=*reinterpret_cast<const float4*>(&Xs[ty4+i][ecol+4]);
    xa.x+=yacc[i][0]+b2a.x; xa.y+=yacc[i][1]+b2a.y; xa.z+=yacc[i][2]+b2a.z; xa.w+=yacc[i][3]+b2a.w;
    xb.x+=yacc[i][4]+b2b.x; xb.y+=yacc[i][5]+b2b.y; xb.z+=yacc[i][6]+b2b.z; xb.w+=yacc[i][7]+b2b.w;
    *reinterpret_cast<float4*>(&Xs[ty4+i][ecol])=xa;
    *reinterpret_cast<float4*>(&Xs[ty4+i][ecol+4])=xb;
  }
  __syncthreads();
  int w=t>>6, lane=t&63;
  for (int rl=w; rl<64; rl+=4){
    int r=r0+rl;
    float v0=Xs[rl][lane], v1=Xs[rl][64+lane];
    float s=v0+v1;
    for (int o=32;o>0;o>>=1) s+=__shfl_xor(s,o);
    float mu=s*(1.f/128.f);
    float d0=v0-mu, d1=v1-mu;
    float vv=d0*d0+d1*d1;
    for (int o=32;o>0;o>>=1) vv+=__shfl_xor(vv,o);
    float rsv=rsqrtf(vv*(1.f/128.f)+1e-5f);
    if (r<nf){
      SEo[r*128+lane]=d0*rsv*g[lane]+bb[lane];
      SEo[r*128+64+lane]=d1*rsv*g[64+lane]+bb[64+lane];
    }
  }
}

__global__ __launch_bounds__(256) void k_out(const float* SE, const float* sew, const float* x3d,
    const float* convw, const float* convb, const int* invr, float* out, float* ws){
  (void)ws;
  __shared__ float rows[64][129];
  __shared__ float cw[20*128];
  __shared__ float cb[20];
  __shared__ int rkl[64];
  int t=threadIdx.x;
  int q0=blockIdx.x*64;
  for (int idx=t; idx<20*128; idx+=256) cw[idx]=convw[idx];
  if (t<20) cb[t]=convb[t];
  if (t<64) rkl[t]=invr[q0+t];
  __syncthreads();
  for (int idx=t; idx<64*128; idx+=256){
    int v=idx>>7, e=idx&127;
    int rk=rkl[v];
    rows[v][e]=(rk>=0)? SE[rk*128+e]:sew[(size_t)(q0+v)*128+e];
  }
  __syncthreads();
  for (int idx=t; idx<128*64; idx+=256){
    int c=idx>>6, v=idx&63;
    if (rkl[v]<0) rows[v][c]+=x3d[(size_t)c*NQ+q0+v];
  }
  __syncthreads();
  int v=t&63;
  for (int o=t>>6; o<20; o+=4){
    float a=cb[o];
    const float* cr=cw+o*128;
    for (int c=0;c<128;c++) a+=rows[v][c]*cr[c];
    out[(size_t)o*NQ+q0+v]=a;
  }
}

extern "C" void kernel_launch(void* const* d_in, const int* in_sizes, int n_in,
                              void* d_out, int out_size, void* d_ws, size_t ws_size,
                              hipStream_t stream){
  (void)in_sizes; (void)n_in; (void)out_size; (void)ws_size;
  const float* queries  = (const float*)d_in[0];
  const float* plogits  = (const float*)d_in[1];
  const float* pmasks   = (const float*)d_in[2];
  const float* x3d      = (const float*)d_in[3];
  const float* depth    = (const float*)d_in[4];
  const float* Kmat     = (const float*)d_in[5];
  const float* Emat     = (const float*)d_in[6];
  const float* vorigin  = (const float*)d_in[7];
  const int*   fov      = (const int*)d_in[8];
  const float* sew      = (const float*)d_in[9];
  const float* instposw = (const float*)d_in[10];
  const float* posw     = (const float*)d_in[11];
  const float* convw    = (const float*)d_in[12];
  const float* convb    = (const float*)d_in[13];
  const float* AW       = (const float*)d_in[14];
  const float* AB       = (const float*)d_in[15];
  const float* LG       = (const float*)d_in[16];
  const float* LB       = (const float*)d_in[17];
  const float* F1W      = (const float*)d_in[18];
  const float* F1B      = (const float*)d_in[19];
  const float* F2W      = (const float*)d_in[20];
  const float* F2B      = (const float*)d_in[21];
  float* out = (float*)d_out;
  char* wsb = (char*)d_ws;
  float* fws = (float*)d_ws;
  int* fidx = (int*)(wsb + OFF_FIDX);
  int* invr = (int*)(wsb + OFF_INV);
  float* W1T = (float*)(wsb + OFF_W1T);
  float* W2T = (float*)(wsb + OFF_W2T);
  float* SE = (float*)(wsb + OFF_SE);
  float* A1 = (float*)(wsb + OFF_A1);
  float* A2 = (float*)(wsb + OFF_A2);
  float* SC = (float*)(wsb + OFF_SC);

  auto aw  = [&](int i,int br,int m){ return AW + (size_t)(((i*2+br)*4+m))*128*128; };
  auto ab  = [&](int i,int br,int m){ return AB + (size_t)(((i*2+br)*4+m))*128; };
  auto lng = [&](int i,int br,int wch){ return LG + (size_t)(((i*2+br)*2+wch))*128; };
  auto lnb = [&](int i,int br,int wch){ return LB + (size_t)(((i*2+br)*2+wch))*128; };
  auto f1w = [&](int i,int br){ return F1W + (size_t)(i*2+br)*512*128; };
  auto f1b = [&](int i,int br){ return F1B + (size_t)(i*2+br)*512; };
  auto f2w = [&](int i,int br){ return F2W + (size_t)(i*2+br)*128*512; };
  auto f2b = [&](int i,int br){ return F2B + (size_t)(i*2+br)*128; };

  const int NB64 = NF_MAX/64;   // 1152

  k_init<<<1,256,0,stream>>>(Kmat,Emat,fws);
  k_score<<<1,320,0,stream>>>(plogits,fws);
  k_winner<<<NPIX/256,256,0,stream>>>(pmasks,depth,fws);
  k_sel<<<1,256,0,stream>>>(queries,instposw,posw,fws);
  k_fov_count<<<256,256,0,stream>>>(fov,fws);
  k_fov_scan<<<1,64,0,stream>>>(fws);
  k_fov_scatter<<<256,256,0,stream>>>(fov,fws);
  k_se_build<<<NB64,256,0,stream>>>(sew,x3d,fidx,SE,fws);

  for (int i=0;i<2;i++){
    // ---- instance-side layer (queries = instances, keys/vals = scene) ----
    kA_prep<<<1,256,0,stream>>>(aw(i,0,0),ab(i,0,0),aw(i,0,1),ab(i,0,1),fws);
    kS1<<<NB64,256,0,stream>>>(SE,SC,posw,vorigin,fidx,fws);
    kS2S3<<<IH_MAX,256,0,stream>>>(SC,fws);
    kS4<<<256,256,0,stream>>>(SC,SE,fws);
    kA_post<<<1,256,0,stream>>>(aw(i,0,2),ab(i,0,2),aw(i,0,3),ab(i,0,3),lng(i,0,0),lnb(i,0,0),fws);
    kA_ffn<<<INST_MAX,256,0,stream>>>(f1w(i,0),f1b(i,0),f2w(i,0),f2b(i,0),lng(i,0,1),lnb(i,0,1),fws);
    kA_kv<<<1,256,0,stream>>>(aw(i,1,1),ab(i,1,1),aw(i,1,2),ab(i,1,2),fws);
    // ---- scene-side layer (queries = scene, keys/vals = instances) ----
    kQ<<<NB64,256,0,stream>>>(A1,aw(i,1,0),ab(i,1,0),SE,fidx,posw,vorigin,fws);
    kAttnOLN<<<NB64,256,0,stream>>>(A1,A2,aw(i,1,3),ab(i,1,3),lng(i,1,0),lnb(i,1,0),SE,fidx,posw,vorigin,fws);
    k_transpose<<<dim3(4,16),dim3(32,8),0,stream>>>(f1w(i,1),W1T,512,128);
    k_transpose<<<dim3(16,4),dim3(32,8),0,stream>>>(f2w(i,1),W2T,128,512);
    kFFN<<<NB64,256,0,stream>>>(A2,SE,W1T,W2T,f1b(i,1),f2b(i,1),lng(i,1,1),lnb(i,1,1),fws);
  }
  k_out<<<NQ/64,256,0,stream>>>(SE,sew,x3d,convw,convb,invr,out,fws);
}

// Round 5
// 2566.991 us; speedup vs baseline: 1.0155x; 1.0155x over previous
//
#include <hip/hip_runtime.h>
#include <math.h>

#define EMBED 128
#define NCLS 21
#define NI_ 300
#define IMH 96
#define IMW 320
#define NPIX (IMH*IMW)
#define NQ 262144
#define NF_MAX 73728
#define INST_MAX 16
#define IH_MAX 64
#define RS32 0.17677669529663687f

// ---- SMALL region layout (4-byte units at ws base) ----
#define S_NF 0
#define S_NK 1
#define S_NINST 2
#define S_NIH 3
#define S_INVK 8      // 9 f
#define S_INVE 24     // 16 f
#define S_KIDX 64     // 300 i
#define S_SKK 400     // 300 f
#define S_MAREA 768   // 300 i
#define S_PAREA 1088  // 300 i
#define S_AREA2 1408  // 300 i
#define S_XYZ 1728    // 900 f
#define S_SELJ 2656   // 16 i
#define S_K2 2688     // 16 i
#define S_FCNT 3072   // 256 i
#define S_FOFF 3328   // 256 i
#define S_INSTQ 4096  // 16*128 f
#define S_INSTP 6144
#define S_QIN 8192
#define S_QH 10240
#define S_XI 12288
#define S_KHB 16384
#define S_VHB 18432
#define S_QKT 20480   // 64*128 f
#define S_SB 28672    // 64 f
#define S_SUMV 28928  // 64 f
#define S_WSUM 29056  // 64*128 f

#define OFF_FIDX ((size_t)1<<20)
#define OFF_INV  ((size_t)2<<20)
#define OFF_W1T  ((size_t)3<<20)
#define OFF_W2T  (((size_t)3<<20) + 512*128*4)
#define OFF_SE   ((size_t)4<<20)
#define SE_BYTES ((size_t)NF_MAX*128*4)
#define OFF_A1   (OFF_SE + SE_BYTES)
#define OFF_A2   (OFF_A1 + SE_BYTES)
#define OFF_SC   (OFF_A2 + SE_BYTES)

__global__ __launch_bounds__(256) void k_init(const float* Km, const float* Em, float* ws){
  int* iw = (int*)ws;
  for (int i = threadIdx.x; i < 4096; i += 256) iw[i] = 0;
  __syncthreads();
  if (threadIdx.x == 0){
    float* fw = ws;
    const float* K = Km;
    float A = K[4]*K[8]-K[5]*K[7];
    float B = K[5]*K[6]-K[3]*K[8];
    float C = K[3]*K[7]-K[4]*K[6];
    float det = K[0]*A + K[1]*B + K[2]*C;
    float id = 1.0f/det;
    fw[S_INVK+0] = A*id;
    fw[S_INVK+1] = (K[2]*K[7]-K[1]*K[8])*id;
    fw[S_INVK+2] = (K[1]*K[5]-K[2]*K[4])*id;
    fw[S_INVK+3] = B*id;
    fw[S_INVK+4] = (K[0]*K[8]-K[2]*K[6])*id;
    fw[S_INVK+5] = (K[2]*K[3]-K[0]*K[5])*id;
    fw[S_INVK+6] = C*id;
    fw[S_INVK+7] = (K[1]*K[6]-K[0]*K[7])*id;
    fw[S_INVK+8] = (K[0]*K[4]-K[1]*K[3])*id;
    // 4x4 Gauss-Jordan inverse of E
    float M[4][8];
    for (int r=0;r<4;r++){ for(int c=0;c<4;c++){ M[r][c]=Em[r*4+c]; M[r][4+c]=(r==c)?1.f:0.f; } }
    for (int col=0; col<4; col++){
      int piv=col; float best=fabsf(M[col][col]);
      for (int r=col+1;r<4;r++){ float v=fabsf(M[r][col]); if(v>best){best=v;piv=r;} }
      if (piv!=col){ for(int c=0;c<8;c++){ float tmp=M[col][c]; M[col][c]=M[piv][c]; M[piv][c]=tmp; } }
      float inv=1.0f/M[col][col];
      for (int c=0;c<8;c++) M[col][c]*=inv;
      for (int r=0;r<4;r++){ if(r==col) continue; float f=M[r][col]; for(int c=0;c<8;c++) M[r][c]-=f*M[col][c]; }
    }
    for (int r=0;r<4;r++) for(int c=0;c<4;c++) fw[S_INVE+r*4+c]=M[r][4+c];
  }
}

__global__ __launch_bounds__(320) void k_score(const float* logits, float* ws){
  int* iw=(int*)ws; float* fw=ws;
  __shared__ float ssc[NI_];
  __shared__ int skp[NI_];
  int t=threadIdx.x;
  if (t < NI_){
    float v[NCLS]; float mx=-1e30f;
    for (int c=0;c<NCLS;c++){
      float l=logits[t*NCLS+c];
      float sg=1.0f/(1.0f+expf(-l));
      float x=sg/0.06f;
      v[c]=x; mx=fmaxf(mx,x);
    }
    float s=0.f;
    for (int c=0;c<NCLS;c++) s += expf(v[c]-mx);
    float score=1.0f/s;     // max softmax prob
    ssc[t]=score; skp[t]=(score>0.25f)?1:0;
  }
  __syncthreads();
  if (t==0){
    int nk=0;
    for (int i=0;i<NI_;i++){ if(skp[i]){ iw[S_KIDX+nk]=i; fw[S_SKK+nk]=ssc[i]; nk++; } }
    iw[S_NK]=nk;
  }
}

// Block-level pre-reduction: per-query partial counts/sums in LDS, then
// at most nk*6 global atomics per block.
__global__ __launch_bounds__(256) void k_winner(const float* pmask, const float* depth, float* ws){
  int* iw=(int*)ws; float* fw=ws;
  int nk=iw[S_NK];
  if (nk>NI_) nk=NI_;
  __shared__ int s_pa[NI_], s_ma[NI_], s_a2[NI_];
  __shared__ float s_x[NI_], s_y[NI_], s_z[NI_];
  __shared__ int s_gi[NI_];
  __shared__ float s_sc[NI_];
  int t=threadIdx.x;
  int lane=t&63;
  for (int j=t;j<nk;j+=256){
    s_pa[j]=0; s_ma[j]=0; s_a2[j]=0;
    s_x[j]=0.f; s_y[j]=0.f; s_z[j]=0.f;
    s_gi[j]=iw[S_KIDX+j]; s_sc[j]=fw[S_SKK+j];
  }
  __syncthreads();
  int p=blockIdx.x*256+t;
  float best=-1e30f; int jw=-1; float mw=0.f;
  for (int j=0;j<nk;j++){
    float m=1.0f/(1.0f+expf(-pmask[(size_t)s_gi[j]*NPIX+p]));
    unsigned long long msk=__ballot(m>=0.5f);
    if (lane==0 && msk) atomicAdd(&s_pa[j], __popcll(msk));
    float wv=s_sc[j]*m;
    if (wv>best){ best=wv; jw=j; mw=m; }
  }
  if (jw>=0){
    atomicAdd(&s_ma[jw],1);
    if (mw>=0.5f){
      atomicAdd(&s_a2[jw],1);
      float d=depth[p];
      float gx=(float)(p%IMW)*4.0f, gy=(float)(p/IMW)*4.0f;
      float X=gx*d, Y=gy*d;
      const float* iK=fw+S_INVK; const float* iE=fw+S_INVE;
      float c0=iK[0]*X+iK[1]*Y+iK[2]*d;
      float c1=iK[3]*X+iK[4]*Y+iK[5]*d;
      float c2=iK[6]*X+iK[7]*Y+iK[8]*d;
      float wx=iE[0]*c0+iE[1]*c1+iE[2]*c2+iE[3];
      float wy=iE[4]*c0+iE[5]*c1+iE[6]*c2+iE[7];
      float wz=iE[8]*c0+iE[9]*c1+iE[10]*c2+iE[11];
      atomicAdd(&s_x[jw],wx);
      atomicAdd(&s_y[jw],wy);
      atomicAdd(&s_z[jw],wz);
    }
  }
  __syncthreads();
  for (int j=t;j<nk;j+=256){
    if (s_pa[j]) atomicAdd(&iw[S_PAREA+j],s_pa[j]);
    if (s_ma[j]) atomicAdd(&iw[S_MAREA+j],s_ma[j]);
    if (s_a2[j]) atomicAdd(&iw[S_AREA2+j],s_a2[j]);
    if (s_x[j]!=0.f) atomicAdd(&fw[S_XYZ+j*3+0],s_x[j]);
    if (s_y[j]!=0.f) atomicAdd(&fw[S_XYZ+j*3+1],s_y[j]);
    if (s_z[j]!=0.f) atomicAdd(&fw[S_XYZ+j*3+2],s_z[j]);
  }
}

__global__ __launch_bounds__(256) void k_sel(const float* queries, const float* instposw, const float* posw, float* ws){
  int* iw=(int*)ws; float* fw=ws;
  __shared__ int sn;
  if (threadIdx.x==0){
    int nk=iw[S_NK]; int n=0;
    for (int j=0;j<nk;j++){
      int a2=iw[S_AREA2+j];
      if (a2>0){
        float r=(float)iw[S_MAREA+j]/(float)iw[S_PAREA+j];
        if (r>=0.8f && n<INST_MAX){ iw[S_SELJ+n]=j; iw[S_K2+n]=iw[S_KIDX+j]; n++; }
      }
    }
    iw[S_NINST]=n; iw[S_NIH]=4*n; sn=n;
  }
  __syncthreads();
  int n=sn;
  for (int idx=threadIdx.x; idx<n*128; idx+=256){
    int i=idx>>7, e=idx&127;
    int j=iw[S_SELJ+i]; int gi=iw[S_K2+i];
    fw[S_INSTQ+idx]=queries[gi*128+e];
    float mp=fw[S_XYZ+j*3]*posw[e*3]+fw[S_XYZ+j*3+1]*posw[e*3+1]+fw[S_XYZ+j*3+2]*posw[e*3+2];
    fw[S_INSTP+idx]=instposw[gi*128+e]+mp;
  }
}

__global__ __launch_bounds__(256) void k_fov_count(const int* fov, float* ws){
  int* iw=(int*)ws;
  __shared__ int red[256];
  int t=threadIdx.x;
  int base=blockIdx.x*1024;
  int s=0;
  for (int k=0;k<4;k++) s += (fov[base+k*256+t]!=0)?1:0;
  red[t]=s; __syncthreads();
  for (int st=128;st>0;st>>=1){ if(t<st) red[t]+=red[t+st]; __syncthreads(); }
  if (t==0) iw[S_FCNT+blockIdx.x]=red[0];
}

__global__ void k_fov_scan(float* ws){
  int* iw=(int*)ws;
  if (threadIdx.x==0){
    int acc=0;
    for (int b=0;b<256;b++){ iw[S_FOFF+b]=acc; acc+=iw[S_FCNT+b]; }
    iw[S_NF]=(acc<NF_MAX)?acc:NF_MAX;
  }
}

__global__ __launch_bounds__(256) void k_fov_scatter(const int* fov, float* ws){
  int* iw=(int*)ws;
  int* fidx=(int*)((char*)ws+OFF_FIDX);
  int* invr=(int*)((char*)ws+OFF_INV);
  __shared__ int wsums[4];
  __shared__ int woff[4];
  __shared__ int cur;
  __shared__ int tot;
  int t=threadIdx.x; int w=t>>6; int lane=t&63;
  if (t==0) cur=iw[S_FOFF+blockIdx.x];
  __syncthreads();
  int base=blockIdx.x*1024;
  for (int k=0;k<4;k++){
    int i=base+k*256+t;
    int f=(fov[i]!=0)?1:0;
    unsigned long long m=__ballot(f);
    int rk=__popcll(m & ((lane==0)?0ull:((~0ull)>>(64-lane))));
    if (lane==0) wsums[w]=__popcll(m);
    __syncthreads();
    if (t==0){ int a=0; for(int q2=0;q2<4;q2++){ woff[q2]=a; a+=wsums[q2]; } tot=a; }
    __syncthreads();
    if (f){
      int r=cur+woff[w]+rk;
      if (r<NF_MAX){ fidx[r]=i; invr[i]=r; } else invr[i]=-1;
    } else invr[i]=-1;
    __syncthreads();
    if (t==0) cur+=tot;
    __syncthreads();
  }
}

__global__ __launch_bounds__(256) void k_se_build(const float* sew, const float* x3d, const int* fidx, float* SE, float* ws){
  int* iw=(int*)ws;
  int nf=iw[S_NF];
  int r0=blockIdx.x*64;
  if (r0>=nf) return;
  int nr=min(64,nf-r0);
  __shared__ float tile[64][129];
  __shared__ int fidxl[64];
  int t=threadIdx.x;
  if (t<64) fidxl[t]=(t<nr)? fidx[r0+t]:0;
  __syncthreads();
  for (int idx=t; idx<64*128; idx+=256){
    int v=idx>>7, e=idx&127;
    tile[v][e]=(v<nr)? sew[(size_t)fidxl[v]*128+e]:0.f;
  }
  __syncthreads();
  for (int idx=t; idx<128*64; idx+=256){
    int c=idx>>6, v=idx&63;
    if (v<nr) tile[v][c]+=x3d[(size_t)c*NQ+fidxl[v]];
  }
  __syncthreads();
  for (int idx=t; idx<64*128; idx+=256){
    int v=idx>>7, e=idx&127;
    if (v<nr) SE[(r0+v)*128+e]=tile[v][e];
  }
}

__global__ __launch_bounds__(256) void kA_prep(const float* Wq, const float* bq, const float* Wk, const float* bk, float* ws){
  int* iw=(int*)ws; float* fw=ws;
  int n=iw[S_NINST]; int nih=iw[S_NIH];
  int t=threadIdx.x;
  for (int idx=t; idx<n*128; idx+=256) fw[S_QIN+idx]=fw[S_INSTQ+idx]+fw[S_INSTP+idx];
  __syncthreads();
  for (int idx=t; idx<n*128; idx+=256){
    int i=idx>>7, e=idx&127;
    float a=bq[e];
    for (int k=0;k<128;k++) a+=fw[S_QIN+i*128+k]*Wq[e*128+k];
    fw[S_QH+idx]=a;
  }
  __syncthreads();
  for (int idx=t; idx<nih*128; idx+=256){
    int ih=idx>>7, e=idx&127;
    int i=ih>>2, h=ih&3;
    float a=0.f;
    for (int d=0;d<32;d++) a+=fw[S_QH+i*128+h*32+d]*Wk[(h*32+d)*128+e];
    fw[S_QKT+idx]=a*RS32;
  }
  for (int ih=t; ih<nih; ih+=256){
    int i=ih>>2, h=ih&3;
    float a=0.f;
    for (int d=0;d<32;d++) a+=fw[S_QH+i*128+h*32+d]*bk[h*32+d];
    fw[S_SB+ih]=a*RS32;
  }
}

// kS1 v2: SC[ih][r] = sb[ih] + qk[ih][:] . xt[r][:]  as a register-tiled
// 64x64x128 GEMM (4x4/thread). qk zero-padded to 64 rows; both operands read
// via ds_read_b128 (qk rows broadcast across tx; xt rows tok=tx+16j => uniform
// bank spread). Replaces the 2-LDS-b32-per-FMA serial loop (~180us/dispatch).
__global__ __launch_bounds__(256) void kS1(const float* SE, float* SC, const float* posw, const float* org, const int* fidx, float* ws){
  int* iw=(int*)ws; float* fw=ws;
  int nf=iw[S_NF]; int nih=iw[S_NIH];
  int r0=blockIdx.x*64;
  if (r0>=nf || nih==0) return;
  int nr=min(64,nf-r0);
  __shared__ float xt[64][132];
  __shared__ float qk[64][132];
  __shared__ float sbl[64];
  __shared__ float pwl[384];
  __shared__ float px[64],py[64],pz[64];
  __shared__ int fidxl[64];
  int t=threadIdx.x;
  for (int i=t;i<384;i+=256) pwl[i]=posw[i];
  if (t<64) fidxl[t]=(t<nr)? fidx[r0+t]:0;
  for (int idx=t; idx<64*32; idx+=256){
    int ih=idx>>5, e4=(idx&31)*4;
    float4 v = (ih<nih)? *reinterpret_cast<const float4*>(&fw[S_QKT+ih*128+e4])
                       : make_float4(0.f,0.f,0.f,0.f);
    *reinterpret_cast<float4*>(&qk[ih][e4]) = v;
  }
  if (t<64) sbl[t]=(t<nih)? fw[S_SB+t]:0.f;
  __syncthreads();
  if (t<64){
    int q=fidxl[t];
    int vx=q>>11, vy=(q>>4)&127, vz=q&15;
    px[t]=(vx+0.5f)*0.2f+org[0];
    py[t]=(vy+0.5f)*0.2f+org[1];
    pz[t]=(vz+0.5f)*0.2f+org[2];
  }
  __syncthreads();
  for (int idx=t; idx<64*32; idx+=256){
    int v=idx>>5, e4=(idx&31)*4;
    float4 s=make_float4(0.f,0.f,0.f,0.f);
    if (v<nr){
      s=*reinterpret_cast<const float4*>(SE+(size_t)(r0+v)*128+e4);
      float X=px[v], Y=py[v], Z=pz[v];
      s.x+=X*pwl[(e4+0)*3]+Y*pwl[(e4+0)*3+1]+Z*pwl[(e4+0)*3+2];
      s.y+=X*pwl[(e4+1)*3]+Y*pwl[(e4+1)*3+1]+Z*pwl[(e4+1)*3+2];
      s.z+=X*pwl[(e4+2)*3]+Y*pwl[(e4+2)*3+1]+Z*pwl[(e4+2)*3+2];
      s.w+=X*pwl[(e4+3)*3]+Y*pwl[(e4+3)*3+1]+Z*pwl[(e4+3)*3+2];
    }
    *reinterpret_cast<float4*>(&xt[v][e4])=s;
  }
  __syncthreads();
  int tx=t&15, ty=t>>4;
  int ih0=ty*4;
  float acc[4][4];
  #pragma unroll
  for (int i=0;i<4;i++)
    #pragma unroll
    for (int j=0;j<4;j++) acc[i][j]=0.f;
  for (int k=0;k<128;k+=4){
    float4 q0=*reinterpret_cast<const float4*>(&qk[ih0+0][k]);
    float4 q1=*reinterpret_cast<const float4*>(&qk[ih0+1][k]);
    float4 q2=*reinterpret_cast<const float4*>(&qk[ih0+2][k]);
    float4 q3=*reinterpret_cast<const float4*>(&qk[ih0+3][k]);
    #pragma unroll
    for (int j=0;j<4;j++){
      float4 x=*reinterpret_cast<const float4*>(&xt[tx+16*j][k]);
      acc[0][j]+=q0.x*x.x+q0.y*x.y+q0.z*x.z+q0.w*x.w;
      acc[1][j]+=q1.x*x.x+q1.y*x.y+q1.z*x.z+q1.w*x.w;
      acc[2][j]+=q2.x*x.x+q2.y*x.y+q2.z*x.z+q2.w*x.w;
      acc[3][j]+=q3.x*x.x+q3.y*x.y+q3.z*x.z+q3.w*x.w;
    }
  }
  #pragma unroll
  for (int i=0;i<4;i++){
    int ih=ih0+i;
    if (ih>=nih) break;
    float sb=sbl[ih];
    #pragma unroll
    for (int j=0;j<4;j++){
      int tok=tx+16*j;
      if (tok<nr) SC[(size_t)ih*NF_MAX+r0+tok]=acc[i][j]+sb;
    }
  }
}

__global__ __launch_bounds__(256) void kS2S3(float* SC, float* ws){
  int* iw=(int*)ws; float* fw=ws;
  int nih=iw[S_NIH]; int ih=blockIdx.x;
  if (ih>=nih) return;
  int nf=iw[S_NF];
  float* row=SC+(size_t)ih*NF_MAX;
  __shared__ float red[256];
  int t=threadIdx.x;
  float m=-1e30f;
  for (int j=t;j<nf;j+=256) m=fmaxf(m,row[j]);
  red[t]=m; __syncthreads();
  for (int s=128;s>0;s>>=1){ if(t<s) red[t]=fmaxf(red[t],red[t+s]); __syncthreads(); }
  m=red[0]; __syncthreads();
  float sum=0.f;
  for (int j=t;j<nf;j+=256){ float p=expf(row[j]-m); row[j]=p; sum+=p; }
  red[t]=sum; __syncthreads();
  for (int s=128;s>0;s>>=1){ if(t<s) red[t]+=red[t+s]; __syncthreads(); }
  if (t==0) fw[S_SUMV+ih]=red[0];
  if (t<128) fw[S_WSUM+ih*128+t]=0.f;
}

// kS4 v2: WSUM[ih][e] += sum_j SC[ih][j]*SE[j][e] with direct global/L1 reads
// (SC row values broadcast-merge in-wave; SE float4 coalesced). No LDS at all;
// 4x8 register accumulator; guarded atomics (rows ih<nih only).
__global__ __launch_bounds__(256) void kS4(const float* __restrict__ SC, const float* __restrict__ SE, float* __restrict__ ws){
  int* iw=(int*)ws; float* fw=ws;
  int nf=iw[S_NF]; int nih=iw[S_NIH];
  if (nih==0) return;
  int t=threadIdx.x;
  int chunk=(nf+255)/256;
  int j0=blockIdx.x*chunk;
  int j1=min(nf,j0+chunk);
  if (j0>=j1) return;
  int tx=t&15, ty=t>>4;
  int ecol=tx*8, ih0=ty*4;
  const float* sc0=SC+(size_t)(ih0+0)*NF_MAX;
  const float* sc1=SC+(size_t)(ih0+1)*NF_MAX;
  const float* sc2=SC+(size_t)(ih0+2)*NF_MAX;
  const float* sc3=SC+(size_t)(ih0+3)*NF_MAX;
  bool g0=ih0+0<nih, g1=ih0+1<nih, g2=ih0+2<nih, g3=ih0+3<nih;
  float acc[4][8];
  #pragma unroll
  for (int i=0;i<4;i++)
    #pragma unroll
    for (int j=0;j<8;j++) acc[i][j]=0.f;
  #pragma unroll 4
  for (int j=j0;j<j1;j++){
    float4 sa=*reinterpret_cast<const float4*>(SE+(size_t)j*128+ecol);
    float4 sb=*reinterpret_cast<const float4*>(SE+(size_t)j*128+ecol+4);
    float s0=g0? sc0[j]:0.f;
    float s1=g1? sc1[j]:0.f;
    float s2=g2? sc2[j]:0.f;
    float s3=g3? sc3[j]:0.f;
    acc[0][0]+=s0*sa.x; acc[0][1]+=s0*sa.y; acc[0][2]+=s0*sa.z; acc[0][3]+=s0*sa.w;
    acc[0][4]+=s0*sb.x; acc[0][5]+=s0*sb.y; acc[0][6]+=s0*sb.z; acc[0][7]+=s0*sb.w;
    acc[1][0]+=s1*sa.x; acc[1][1]+=s1*sa.y; acc[1][2]+=s1*sa.z; acc[1][3]+=s1*sa.w;
    acc[1][4]+=s1*sb.x; acc[1][5]+=s1*sb.y; acc[1][6]+=s1*sb.z; acc[1][7]+=s1*sb.w;
    acc[2][0]+=s2*sa.x; acc[2][1]+=s2*sa.y; acc[2][2]+=s2*sa.z; acc[2][3]+=s2*sa.w;
    acc[2][4]+=s2*sb.x; acc[2][5]+=s2*sb.y; acc[2][6]+=s2*sb.z; acc[2][7]+=s2*sb.w;
    acc[3][0]+=s3*sa.x; acc[3][1]+=s3*sa.y; acc[3][2]+=s3*sa.z; acc[3][3]+=s3*sa.w;
    acc[3][4]+=s3*sb.x; acc[3][5]+=s3*sb.y; acc[3][6]+=s3*sb.z; acc[3][7]+=s3*sb.w;
  }
  #pragma unroll
  for (int i=0;i<4;i++){
    int ih=ih0+i;
    if (ih>=nih) break;
    #pragma unroll
    for (int jj=0;jj<8;jj++)
      atomicAdd(&fw[S_WSUM+ih*128+ecol+jj], acc[i][jj]);
  }
}

__global__ __launch_bounds__(256) void kA_post(const float* Wv, const float* bv, const float* Wo, const float* bo,
    const float* g, const float* bb, float* ws){
  int* iw=(int*)ws; float* fw=ws;
  int n=iw[S_NINST]; int nih=iw[S_NIH];
  __shared__ float wn[IH_MAX*128];
  __shared__ float ol[INST_MAX*128];
  __shared__ float tl[INST_MAX*128];
  int t=threadIdx.x;
  for (int idx=t; idx<nih*128; idx+=256){
    int ih=idx>>7;
    wn[idx]=fw[S_WSUM+idx]/fw[S_SUMV+ih];
  }
  __syncthreads();
  for (int idx=t; idx<n*128; idx+=256){
    int i=idx>>7, f=idx&127; int h=f>>5;
    float a=bv[f];
    const float* wrow=Wv+f*128;
    const float* wv=wn+(i*4+h)*128;
    for (int e2=0;e2<128;e2++) a+=wrow[e2]*wv[e2];
    ol[idx]=a;
  }
  __syncthreads();
  for (int idx=t; idx<n*128; idx+=256){
    int i=idx>>7, e2=idx&127;
    float a=bo[e2];
    const float* orow=ol+i*128;
    const float* wrow=Wo+e2*128;
    for (int f2=0;f2<128;f2++) a+=orow[f2]*wrow[f2];
    tl[idx]=a+fw[S_QIN+idx];
  }
  __syncthreads();
  int w=t>>6, lane=t&63;
  for (int i=w;i<n;i+=4){
    float v0=tl[i*128+lane], v1=tl[i*128+64+lane];
    float s=v0+v1;
    for (int o=32;o>0;o>>=1) s+=__shfl_xor(s,o);
    float mu=s*(1.f/128.f);
    float d0=v0-mu, d1=v1-mu;
    float vv=d0*d0+d1*d1;
    for (int o=32;o>0;o>>=1) vv+=__shfl_xor(vv,o);
    float rsv=rsqrtf(vv*(1.f/128.f)+1e-5f);
    fw[S_XI+i*128+lane]=d0*rsv*g[lane]+bb[lane];
    fw[S_XI+i*128+64+lane]=d1*rsv*g[64+lane]+bb[64+lane];
  }
}

__global__ __launch_bounds__(256) void kA_ffn(const float* W1, const float* b1, const float* W2, const float* b2,
    const float* g, const float* bb, float* ws){
  int* iw=(int*)ws; float* fw=ws;
  int n=iw[S_NINST];
  int i=blockIdx.x;
  if (i>=n) return;
  __shared__ float xl[128];
  __shared__ float hid[512];
  __shared__ float yv[128];
  int t=threadIdx.x;
  if (t<128) xl[t]=fw[S_XI+i*128+t];
  __syncthreads();
  for (int d=t; d<512; d+=256){
    float a=b1[d];
    const float* wr=W1+d*128;
    for (int k=0;k<128;k++) a+=wr[k]*xl[k];
    hid[d]=fmaxf(a,0.f);
  }
  __syncthreads();
  if (t<128){
    float a=b2[t];
    const float* wr=W2+(size_t)t*512;
    for (int d=0;d<512;d++) a+=wr[d]*hid[d];
    yv[t]=a+xl[t];
  }
  __syncthreads();
  if (t<64){
    float v0=yv[t], v1=yv[t+64];
    float s=v0+v1;
    for (int o=32;o>0;o>>=1) s+=__shfl_xor(s,o);
    float mu=s*(1.f/128.f);
    float d0=v0-mu, d1=v1-mu;
    float vv=d0*d0+d1*d1;
    for (int o=32;o>0;o>>=1) vv+=__shfl_xor(vv,o);
    float rsv=rsqrtf(vv*(1.f/128.f)+1e-5f);
    fw[S_INSTQ+i*128+t]=d0*rsv*g[t]+bb[t];
    fw[S_INSTQ+i*128+64+t]=d1*rsv*g[64+t]+bb[64+t];
  }
}

__global__ __launch_bounds__(256) void kA_kv(const float* Wk2, const float* bk2, const float* Wv2, const float* bv2, float* ws){
  int* iw=(int*)ws; float* fw=ws;
  int n=iw[S_NINST];
  int t=threadIdx.x;
  for (int idx=t; idx<n*128; idx+=256){
    int i=idx>>7, e=idx&127;
    float ak=bk2[e], av=bv2[e];
    const float* wk=Wk2+e*128;
    const float* wv=Wv2+e*128;
    for (int k=0;k<128;k++){
      float qv=fw[S_INSTQ+i*128+k];
      float qp=qv+fw[S_INSTP+i*128+k];
      ak+=qp*wk[k];
      av+=qv*wv[k];
    }
    fw[S_KHB+idx]=ak; fw[S_VHB+idx]=av;
  }
}

// kQ: scene-side q-projection. A1[r][e] = (SE[r]+pos(r)) . Wq[e][:] + bq[e].
__global__ __launch_bounds__(256) void kQ(float* __restrict__ A1,
    const float* __restrict__ Wq, const float* __restrict__ bq,
    const float* __restrict__ SE, const int* __restrict__ fidx,
    const float* __restrict__ posw, const float* __restrict__ org, float* __restrict__ ws){
  int* iw=(int*)ws;
  int nf=iw[S_NF];
  int r0=blockIdx.x*64;
  if (r0>=nf) return;
  __shared__ float Xs[64][132];
  __shared__ float pwl[384];
  __shared__ float px[64],py[64],pz[64];
  int t=threadIdx.x;
  for (int i=t;i<384;i+=256) pwl[i]=posw[i];
  if (t<64){
    int r=r0+t;
    int q=(r<nf)? fidx[r]:0;
    int vx=q>>11, vy=(q>>4)&127, vz=q&15;
    px[t]=(vx+0.5f)*0.2f+org[0];
    py[t]=(vy+0.5f)*0.2f+org[1];
    pz[t]=(vz+0.5f)*0.2f+org[2];
  }
  __syncthreads();
  for (int idx=t; idx<64*32; idx+=256){
    int rl=idx>>5, e4=(idx&31)*4;
    float4 v=*reinterpret_cast<const float4*>(SE+(size_t)(r0+rl)*128+e4);
    float X=px[rl], Y=py[rl], Z=pz[rl];
    v.x+=X*pwl[(e4+0)*3]+Y*pwl[(e4+0)*3+1]+Z*pwl[(e4+0)*3+2];
    v.y+=X*pwl[(e4+1)*3]+Y*pwl[(e4+1)*3+1]+Z*pwl[(e4+1)*3+2];
    v.z+=X*pwl[(e4+2)*3]+Y*pwl[(e4+2)*3+1]+Z*pwl[(e4+2)*3+2];
    v.w+=X*pwl[(e4+3)*3]+Y*pwl[(e4+3)*3+1]+Z*pwl[(e4+3)*3+2];
    *reinterpret_cast<float4*>(&Xs[rl][e4])=v;
  }
  __syncthreads();
  int tx=t&15, ty=t>>4, ty4=ty*4, ecol=tx*8;
  float acc[4][8];
  #pragma unroll
  for (int i=0;i<4;i++)
    #pragma unroll
    for (int j=0;j<8;j++) acc[i][j]=0.f;
  for (int k=0;k<128;k+=4){
    float4 xv0=*reinterpret_cast<const float4*>(&Xs[ty4+0][k]);
    float4 xv1=*reinterpret_cast<const float4*>(&Xs[ty4+1][k]);
    float4 xv2=*reinterpret_cast<const float4*>(&Xs[ty4+2][k]);
    float4 xv3=*reinterpret_cast<const float4*>(&Xs[ty4+3][k]);
    #pragma unroll
    for (int jj=0;jj<8;jj++){
      float4 w=*reinterpret_cast<const float4*>(Wq+(size_t)(ecol+jj)*128+k);
      acc[0][jj]+=xv0.x*w.x+xv0.y*w.y+xv0.z*w.z+xv0.w*w.w;
      acc[1][jj]+=xv1.x*w.x+xv1.y*w.y+xv1.z*w.z+xv1.w*w.w;
      acc[2][jj]+=xv2.x*w.x+xv2.y*w.y+xv2.z*w.z+xv2.w*w.w;
      acc[3][jj]+=xv3.x*w.x+xv3.y*w.y+xv3.z*w.z+xv3.w*w.w;
    }
  }
  float4 bqa=*reinterpret_cast<const float4*>(bq+ecol);
  float4 bqb=*reinterpret_cast<const float4*>(bq+ecol+4);
  #pragma unroll
  for (int i=0;i<4;i++){
    int r=r0+ty4+i;
    if (r>=nf) continue;
    float4 o1, o2;
    o1.x=acc[i][0]+bqa.x; o1.y=acc[i][1]+bqa.y; o1.z=acc[i][2]+bqa.z; o1.w=acc[i][3]+bqa.w;
    o2.x=acc[i][4]+bqb.x; o2.y=acc[i][5]+bqb.y; o2.z=acc[i][6]+bqb.z; o2.w=acc[i][7]+bqb.w;
    *reinterpret_cast<float4*>(A1+(size_t)r*128+ecol)=o1;
    *reinterpret_cast<float4*>(A1+(size_t)r*128+ecol+4)=o2;
  }
}

// kAttnOLN: fuses 16-key attention + o-projection + residual(SE+pos) + LN.
__global__ __launch_bounds__(256) void kAttnOLN(const float* __restrict__ A1, float* __restrict__ A2,
    const float* __restrict__ Wo, const float* __restrict__ bo,
    const float* __restrict__ g, const float* __restrict__ bb,
    const float* __restrict__ SE, const int* __restrict__ fidx,
    const float* __restrict__ posw, const float* __restrict__ org, float* __restrict__ ws){
  int* iw=(int*)ws; float* fw=ws;
  int nf=iw[S_NF]; int n=iw[S_NINST];
  int r0=blockIdx.x*64;
  if (r0>=nf) return;
  __shared__ float ot[64][132];
  __shared__ float kh[INST_MAX*128];
  __shared__ float vh[INST_MAX*128];
  __shared__ float pwl[384];
  __shared__ float px[64],py[64],pz[64];
  int t=threadIdx.x;
  for (int idx=t; idx<INST_MAX*128; idx+=256){
    kh[idx]=(idx<n*128)? fw[S_KHB+idx]:0.f;
    vh[idx]=(idx<n*128)? fw[S_VHB+idx]:0.f;
  }
  for (int i=t;i<384;i+=256) pwl[i]=posw[i];
  if (t<64){
    int r=r0+t;
    int q=(r<nf)? fidx[r]:0;
    int vx=q>>11, vy=(q>>4)&127, vz=q&15;
    px[t]=(vx+0.5f)*0.2f+org[0];
    py[t]=(vy+0.5f)*0.2f+org[1];
    pz[t]=(vz+0.5f)*0.2f+org[2];
  }
  for (int idx=t; idx<64*32; idx+=256){
    int rl=idx>>5, e4=(idx&31)*4;
    *reinterpret_cast<float4*>(&ot[rl][e4]) =
      *reinterpret_cast<const float4*>(A1+(size_t)(r0+rl)*128+e4);
  }
  __syncthreads();
  {
    int tokl=t&63, h=t>>6;
    float q[32];
    #pragma unroll
    for (int d8=0;d8<8;d8++){
      float4 v=*reinterpret_cast<const float4*>(&ot[tokl][h*32+d8*4]);
      q[d8*4]=v.x; q[d8*4+1]=v.y; q[d8*4+2]=v.z; q[d8*4+3]=v.w;
    }
    float s[INST_MAX]; float mx=-1e30f;
    for (int j=0;j<INST_MAX;j++){
      float a=0.f;
      #pragma unroll
      for (int d4=0;d4<8;d4++){
        float4 kv=*reinterpret_cast<const float4*>(&kh[j*128+h*32+d4*4]);
        a+=q[d4*4]*kv.x+q[d4*4+1]*kv.y+q[d4*4+2]*kv.z+q[d4*4+3]*kv.w;
      }
      a*=RS32;
      s[j]=(j<n)? a:-1e30f;
      mx=fmaxf(mx,s[j]);
    }
    float sum=0.f;
    for (int j=0;j<INST_MAX;j++){ float p=expf(s[j]-mx); s[j]=p; sum+=p; }
    float inv=(n>0)? 1.0f/sum:0.f;
    float o[32];
    #pragma unroll
    for (int d=0;d<32;d++) o[d]=0.f;
    for (int j=0;j<INST_MAX;j++){
      float a=s[j]*inv;
      #pragma unroll
      for (int d4=0;d4<8;d4++){
        float4 vv=*reinterpret_cast<const float4*>(&vh[j*128+h*32+d4*4]);
        o[d4*4]+=a*vv.x; o[d4*4+1]+=a*vv.y; o[d4*4+2]+=a*vv.z; o[d4*4+3]+=a*vv.w;
      }
    }
    __syncthreads();
    #pragma unroll
    for (int d8=0;d8<8;d8++){
      float4 v; v.x=o[d8*4]; v.y=o[d8*4+1]; v.z=o[d8*4+2]; v.w=o[d8*4+3];
      *reinterpret_cast<float4*>(&ot[tokl][h*32+d8*4])=v;
    }
  }
  __syncthreads();
  int tx=t&15, ty=t>>4, ty4=ty*4, ecol=tx*8;
  float acc[4][8];
  #pragma unroll
  for (int i=0;i<4;i++)
    #pragma unroll
    for (int j=0;j<8;j++) acc[i][j]=0.f;
  for (int k=0;k<128;k+=4){
    float4 xv0=*reinterpret_cast<const float4*>(&ot[ty4+0][k]);
    float4 xv1=*reinterpret_cast<const float4*>(&ot[ty4+1][k]);
    float4 xv2=*reinterpret_cast<const float4*>(&ot[ty4+2][k]);
    float4 xv3=*reinterpret_cast<const float4*>(&ot[ty4+3][k]);
    #pragma unroll
    for (int jj=0;jj<8;jj++){
      float4 w=*reinterpret_cast<const float4*>(Wo+(size_t)(ecol+jj)*128+k);
      acc[0][jj]+=xv0.x*w.x+xv0.y*w.y+xv0.z*w.z+xv0.w*w.w;
      acc[1][jj]+=xv1.x*w.x+xv1.y*w.y+xv1.z*w.z+xv1.w*w.w;
      acc[2][jj]+=xv2.x*w.x+xv2.y*w.y+xv2.z*w.z+xv2.w*w.w;
      acc[3][jj]+=xv3.x*w.x+xv3.y*w.y+xv3.z*w.z+xv3.w*w.w;
    }
  }
  float4 boa=*reinterpret_cast<const float4*>(bo+ecol);
  float4 bob=*reinterpret_cast<const float4*>(bo+ecol+4);
  float4 ga=*reinterpret_cast<const float4*>(g+ecol);
  float4 gb=*reinterpret_cast<const float4*>(g+ecol+4);
  float4 ba=*reinterpret_cast<const float4*>(bb+ecol);
  float4 bbv=*reinterpret_cast<const float4*>(bb+ecol+4);
  float pe[8][3];
  #pragma unroll
  for (int jj=0;jj<8;jj++){
    pe[jj][0]=pwl[(ecol+jj)*3]; pe[jj][1]=pwl[(ecol+jj)*3+1]; pe[jj][2]=pwl[(ecol+jj)*3+2];
  }
  #pragma unroll
  for (int i=0;i<4;i++){
    int r=r0+ty4+i;
    float4 se1=*reinterpret_cast<const float4*>(SE+(size_t)r*128+ecol);
    float4 se2=*reinterpret_cast<const float4*>(SE+(size_t)r*128+ecol+4);
    float X=px[ty4+i], Y=py[ty4+i], Z=pz[ty4+i];
    acc[i][0]+=boa.x+se1.x+X*pe[0][0]+Y*pe[0][1]+Z*pe[0][2];
    acc[i][1]+=boa.y+se1.y+X*pe[1][0]+Y*pe[1][1]+Z*pe[1][2];
    acc[i][2]+=boa.z+se1.z+X*pe[2][0]+Y*pe[2][1]+Z*pe[2][2];
    acc[i][3]+=boa.w+se1.w+X*pe[3][0]+Y*pe[3][1]+Z*pe[3][2];
    acc[i][4]+=bob.x+se2.x+X*pe[4][0]+Y*pe[4][1]+Z*pe[4][2];
    acc[i][5]+=bob.y+se2.y+X*pe[5][0]+Y*pe[5][1]+Z*pe[5][2];
    acc[i][6]+=bob.z+se2.z+X*pe[6][0]+Y*pe[6][1]+Z*pe[6][2];
    acc[i][7]+=bob.w+se2.w+X*pe[7][0]+Y*pe[7][1]+Z*pe[7][2];
    float s1=0.f;
    #pragma unroll
    for (int jj=0;jj<8;jj++) s1+=acc[i][jj];
    s1+=__shfl_xor(s1,1); s1+=__shfl_xor(s1,2); s1+=__shfl_xor(s1,4); s1+=__shfl_xor(s1,8);
    float mu=s1*(1.f/128.f);
    float vv=0.f;
    #pragma unroll
    for (int jj=0;jj<8;jj++){ float d=acc[i][jj]-mu; acc[i][jj]=d; vv+=d*d; }
    vv+=__shfl_xor(vv,1); vv+=__shfl_xor(vv,2); vv+=__shfl_xor(vv,4); vv+=__shfl_xor(vv,8);
    float rsv=rsqrtf(vv*(1.f/128.f)+1e-5f);
    if (r<nf){
      float4 o1,o2;
      o1.x=acc[i][0]*rsv*ga.x+ba.x; o1.y=acc[i][1]*rsv*ga.y+ba.y;
      o1.z=acc[i][2]*rsv*ga.z+ba.z; o1.w=acc[i][3]*rsv*ga.w+ba.w;
      o2.x=acc[i][4]*rsv*gb.x+bbv.x; o2.y=acc[i][5]*rsv*gb.y+bbv.y;
      o2.z=acc[i][6]*rsv*gb.z+bbv.z; o2.w=acc[i][7]*rsv*gb.w+bbv.w;
      *reinterpret_cast<float4*>(A2+(size_t)r*128+ecol)=o1;
      *reinterpret_cast<float4*>(A2+(size_t)r*128+ecol+4)=o2;
    }
  }
}

__global__ void k_transpose(const float* in, float* outp, int R, int C){
  __shared__ float tile[32][33];
  int bx=blockIdx.x*32, by=blockIdx.y*32;
  int tx=threadIdx.x, ty=threadIdx.y;
  for (int k=0;k<4;k++){
    int r=by+ty+k*8, c=bx+tx;
    if (r<R && c<C) tile[ty+k*8][tx]=in[(size_t)r*C+c];
  }
  __syncthreads();
  for (int k=0;k<4;k++){
    int cc=bx+ty+k*8, rr=by+tx;
    if (rr<R && cc<C) outp[(size_t)cc*R+rr]=tile[tx][ty+k*8];
  }
}

// Fused FFN (v1, measured 357us): pinned.
__global__ __launch_bounds__(256) void kFFN(const float* X_, float* SEo, const float* W1T, const float* W2T,
    const float* b1, const float* b2, const float* g, const float* bb, float* ws){
  int* iw=(int*)ws;
  int nf=iw[S_NF];
  int r0=blockIdx.x*64;
  if (r0>=nf) return;
  __shared__ float Xs[64][132];
  __shared__ float Hs[64][68];
  int t=threadIdx.x;
  int tx=t&15, ty=t>>4;
  int ty4=ty*4;
  int ecol=tx*8;
  for (int idx=t; idx<64*32; idx+=256){
    int rl=idx>>5, e4=idx&31;
    int r=r0+rl;
    float4 v = (r<nf)? reinterpret_cast<const float4*>(X_+(size_t)r*128)[e4]
                     : make_float4(0.f,0.f,0.f,0.f);
    *reinterpret_cast<float4*>(&Xs[rl][e4*4]) = v;
  }
  __syncthreads();
  float yacc[4][8];
  #pragma unroll
  for (int i=0;i<4;i++)
    #pragma unroll
    for (int j=0;j<8;j++) yacc[i][j]=0.f;
  for (int dc=0; dc<512; dc+=64){
    int dcol = dc + tx*4;
    float acc[4][4];
    #pragma unroll
    for (int i=0;i<4;i++)
      #pragma unroll
      for (int j=0;j<4;j++) acc[i][j]=0.f;
    for (int k=0;k<128;k+=4){
      float4 w0=*reinterpret_cast<const float4*>(W1T+(size_t)(k+0)*512+dcol);
      float4 w1=*reinterpret_cast<const float4*>(W1T+(size_t)(k+1)*512+dcol);
      float4 w2=*reinterpret_cast<const float4*>(W1T+(size_t)(k+2)*512+dcol);
      float4 w3=*reinterpret_cast<const float4*>(W1T+(size_t)(k+3)*512+dcol);
      #pragma unroll
      for (int i=0;i<4;i++){
        float4 xv=*reinterpret_cast<const float4*>(&Xs[ty4+i][k]);
        acc[i][0]+=xv.x*w0.x; acc[i][1]+=xv.x*w0.y; acc[i][2]+=xv.x*w0.z; acc[i][3]+=xv.x*w0.w;
        acc[i][0]+=xv.y*w1.x; acc[i][1]+=xv.y*w1.y; acc[i][2]+=xv.y*w1.z; acc[i][3]+=xv.y*w1.w;
        acc[i][0]+=xv.z*w2.x; acc[i][1]+=xv.z*w2.y; acc[i][2]+=xv.z*w2.z; acc[i][3]+=xv.z*w2.w;
        acc[i][0]+=xv.w*w3.x; acc[i][1]+=xv.w*w3.y; acc[i][2]+=xv.w*w3.z; acc[i][3]+=xv.w*w3.w;
      }
    }
    float4 b1v=*reinterpret_cast<const float4*>(b1+dcol);
    #pragma unroll
    for (int i=0;i<4;i++){
      float4 h;
      h.x=fmaxf(acc[i][0]+b1v.x,0.f);
      h.y=fmaxf(acc[i][1]+b1v.y,0.f);
      h.z=fmaxf(acc[i][2]+b1v.z,0.f);
      h.w=fmaxf(acc[i][3]+b1v.w,0.f);
      *reinterpret_cast<float4*>(&Hs[ty4+i][tx*4])=h;
    }
    __syncthreads();
    for (int d=0; d<64; d+=4){
      float4 ha0=*reinterpret_cast<const float4*>(&Hs[ty4+0][d]);
      float4 ha1=*reinterpret_cast<const float4*>(&Hs[ty4+1][d]);
      float4 ha2=*reinterpret_cast<const float4*>(&Hs[ty4+2][d]);
      float4 ha3=*reinterpret_cast<const float4*>(&Hs[ty4+3][d]);
      #pragma unroll
      for (int kk=0;kk<4;kk++){
        const float* wrow=W2T+(size_t)(dc+d+kk)*128+ecol;
        float4 wa=*reinterpret_cast<const float4*>(wrow);
        float4 wb=*reinterpret_cast<const float4*>(wrow+4);
        float h0 = (kk==0)?ha0.x:(kk==1)?ha0.y:(kk==2)?ha0.z:ha0.w;
        float h1 = (kk==0)?ha1.x:(kk==1)?ha1.y:(kk==2)?ha1.z:ha1.w;
        float h2 = (kk==0)?ha2.x:(kk==1)?ha2.y:(kk==2)?ha2.z:ha2.w;
        float h3 = (kk==0)?ha3.x:(kk==1)?ha3.y:(kk==2)?ha3.z:ha3.w;
        yacc[0][0]+=h0*wa.x; yacc[0][1]+=h0*wa.y; yacc[0][2]+=h0*wa.z; yacc[0][3]+=h0*wa.w;
        yacc[0][4]+=h0*wb.x; yacc[0][5]+=h0*wb.y; yacc[0][6]+=h0*wb.z; yacc[0][7]+=h0*wb.w;
        yacc[1][0]+=h1*wa.x; yacc[1][1]+=h1*wa.y; yacc[1][2]+=h1*wa.z; yacc[1][3]+=h1*wa.w;
        yacc[1][4]+=h1*wb.x; yacc[1][5]+=h1*wb.y; yacc[1][6]+=h1*wb.z; yacc[1][7]+=h1*wb.w;
        yacc[2][0]+=h2*wa.x; yacc[2][1]+=h2*wa.y; yacc[2][2]+=h2*wa.z; yacc[2][3]+=h2*wa.w;
        yacc[2][4]+=h2*wb.x; yacc[2][5]+=h2*wb.y; yacc[2][6]+=h2*wb.z; yacc[2][7]+=h2*wb.w;
        yacc[3][0]+=h3*wa.x; yacc[3][1]+=h3*wa.y; yacc[3][2]+=h3*wa.z; yacc[3][3]+=h3*wa.w;
        yacc[3][4]+=h3*wb.x; yacc[3][5]+=h3*wb.y; yacc[3][6]+=h3*wb.z; yacc[3][7]+=h3*wb.w;
      }
    }
    __syncthreads();
  }
  float4 b2a=*reinterpret_cast<const float4*>(b2+ecol);
  float4 b2b=*reinterpret_cast<const float4*>(b2+ecol+4);
  #pragma unroll
  for (int i=0;i<4;i++){
    float4 xa=*reinterpret_cast<const float4*>(&Xs[ty4+i][ecol]);
    float4 xb=*reinterpret_cast<const float4*>(&Xs[ty4+i][ecol+4]);
    xa.x+=yacc[i][0]+b2a.x; xa.y+=yacc[i][1]+b2a.y; xa.z+=yacc[i][2]+b2a.z; xa.w+=yacc[i][3]+b2a.w;
    xb.x+=yacc[i][4]+b2b.x; xb.y+=yacc[i][5]+b2b.y; xb.z+=yacc[i][6]+b2b.z; xb.w+=yacc[i][7]+b2b.w;
    *reinterpret_cast<float4*>(&Xs[ty4+i][ecol])=xa;
    *reinterpret_cast<float4*>(&Xs[ty4+i][ecol+4])=xb;
  }
  __syncthreads();
  int w=t>>6, lane=t&63;
  for (int rl=w; rl<64; rl+=4){
    int r=r0+rl;
    float v0=Xs[rl][lane], v1=Xs[rl][64+lane];
    float s=v0+v1;
    for (int o=32;o>0;o>>=1) s+=__shfl_xor(s,o);
    float mu=s*(1.f/128.f);
    float d0=v0-mu, d1=v1-mu;
    float vv=d0*d0+d1*d1;
    for (int o=32;o>0;o>>=1) vv+=__shfl_xor(vv,o);
    float rsv=rsqrtf(vv*(1.f/128.f)+1e-5f);
    if (r<nf){
      SEo[r*128+lane]=d0*rsv*g[lane]+bb[lane];
      SEo[r*128+64+lane]=d1*rsv*g[64+lane]+bb[64+lane];
    }
  }
}

// k_out v2: rows padded to 132 for ds_read_b128; thread = (q, o-slot of 5);
// cw reads are wave-uniform broadcasts. Replaces the 2-LDS-b32-per-FMA loop.
__global__ __launch_bounds__(256) void k_out(const float* SE, const float* sew, const float* x3d,
    const float* convw, const float* convb, const int* invr, float* out, float* ws){
  (void)ws;
  __shared__ float rows[64][132];
  __shared__ float cw[20*128];
  __shared__ float cb[20];
  __shared__ int rkl[64];
  int t=threadIdx.x;
  int q0=blockIdx.x*64;
  for (int idx=t; idx<20*128; idx+=256) cw[idx]=convw[idx];
  if (t<20) cb[t]=convb[t];
  if (t<64) rkl[t]=invr[q0+t];
  __syncthreads();
  for (int idx=t; idx<64*32; idx+=256){
    int v=idx>>5, e4=(idx&31)*4;
    int rk=rkl[v];
    float4 val = (rk>=0)? *reinterpret_cast<const float4*>(SE+(size_t)rk*128+e4)
                        : *reinterpret_cast<const float4*>(sew+(size_t)(q0+v)*128+e4);
    *reinterpret_cast<float4*>(&rows[v][e4])=val;
  }
  __syncthreads();
  for (int idx=t; idx<128*64; idx+=256){
    int c=idx>>6, v=idx&63;
    if (rkl[v]<0) rows[v][c]+=x3d[(size_t)c*NQ+q0+v];
  }
  __syncthreads();
  int v=t&63, slot=t>>6;
  float acc[5]={0.f,0.f,0.f,0.f,0.f};
  for (int c=0;c<128;c+=4){
    float4 rv=*reinterpret_cast<const float4*>(&rows[v][c]);
    #pragma unroll
    for (int oo=0;oo<5;oo++){
      float4 cv=*reinterpret_cast<const float4*>(&cw[(slot*5+oo)*128+c]);
      acc[oo]+=rv.x*cv.x+rv.y*cv.y+rv.z*cv.z+rv.w*cv.w;
    }
  }
  #pragma unroll
  for (int oo=0;oo<5;oo++){
    int o=slot*5+oo;
    out[(size_t)o*NQ+q0+v]=acc[oo]+cb[o];
  }
}

extern "C" void kernel_launch(void* const* d_in, const int* in_sizes, int n_in,
                              void* d_out, int out_size, void* d_ws, size_t ws_size,
                              hipStream_t stream){
  (void)in_sizes; (void)n_in; (void)out_size; (void)ws_size;
  const float* queries  = (const float*)d_in[0];
  const float* plogits  = (const float*)d_in[1];
  const float* pmasks   = (const float*)d_in[2];
  const float* x3d      = (const float*)d_in[3];
  const float* depth    = (const float*)d_in[4];
  const float* Kmat     = (const float*)d_in[5];
  const float* Emat     = (const float*)d_in[6];
  const float* vorigin  = (const float*)d_in[7];
  const int*   fov      = (const int*)d_in[8];
  const float* sew      = (const float*)d_in[9];
  const float* instposw = (const float*)d_in[10];
  const float* posw     = (const float*)d_in[11];
  const float* convw    = (const float*)d_in[12];
  const float* convb    = (const float*)d_in[13];
  const float* AW       = (const float*)d_in[14];
  const float* AB       = (const float*)d_in[15];
  const float* LG       = (const float*)d_in[16];
  const float* LB       = (const float*)d_in[17];
  const float* F1W      = (const float*)d_in[18];
  const float* F1B      = (const float*)d_in[19];
  const float* F2W      = (const float*)d_in[20];
  const float* F2B      = (const float*)d_in[21];
  float* out = (float*)d_out;
  char* wsb = (char*)d_ws;
  float* fws = (float*)d_ws;
  int* fidx = (int*)(wsb + OFF_FIDX);
  int* invr = (int*)(wsb + OFF_INV);
  float* W1T = (float*)(wsb + OFF_W1T);
  float* W2T = (float*)(wsb + OFF_W2T);
  float* SE = (float*)(wsb + OFF_SE);
  float* A1 = (float*)(wsb + OFF_A1);
  float* A2 = (float*)(wsb + OFF_A2);
  float* SC = (float*)(wsb + OFF_SC);

  auto aw  = [&](int i,int br,int m){ return AW + (size_t)(((i*2+br)*4+m))*128*128; };
  auto ab  = [&](int i,int br,int m){ return AB + (size_t)(((i*2+br)*4+m))*128; };
  auto lng = [&](int i,int br,int wch){ return LG + (size_t)(((i*2+br)*2+wch))*128; };
  auto lnb = [&](int i,int br,int wch){ return LB + (size_t)(((i*2+br)*2+wch))*128; };
  auto f1w = [&](int i,int br){ return F1W + (size_t)(i*2+br)*512*128; };
  auto f1b = [&](int i,int br){ return F1B + (size_t)(i*2+br)*512; };
  auto f2w = [&](int i,int br){ return F2W + (size_t)(i*2+br)*128*512; };
  auto f2b = [&](int i,int br){ return F2B + (size_t)(i*2+br)*128; };

  const int NB64 = NF_MAX/64;   // 1152

  k_init<<<1,256,0,stream>>>(Kmat,Emat,fws);
  k_score<<<1,320,0,stream>>>(plogits,fws);
  k_winner<<<NPIX/256,256,0,stream>>>(pmasks,depth,fws);
  k_sel<<<1,256,0,stream>>>(queries,instposw,posw,fws);
  k_fov_count<<<256,256,0,stream>>>(fov,fws);
  k_fov_scan<<<1,64,0,stream>>>(fws);
  k_fov_scatter<<<256,256,0,stream>>>(fov,fws);
  k_se_build<<<NB64,256,0,stream>>>(sew,x3d,fidx,SE,fws);

  for (int i=0;i<2;i++){
    // ---- instance-side layer (queries = instances, keys/vals = scene) ----
    kA_prep<<<1,256,0,stream>>>(aw(i,0,0),ab(i,0,0),aw(i,0,1),ab(i,0,1),fws);
    kS1<<<NB64,256,0,stream>>>(SE,SC,posw,vorigin,fidx,fws);
    kS2S3<<<IH_MAX,256,0,stream>>>(SC,fws);
    kS4<<<256,256,0,stream>>>(SC,SE,fws);
    kA_post<<<1,256,0,stream>>>(aw(i,0,2),ab(i,0,2),aw(i,0,3),ab(i,0,3),lng(i,0,0),lnb(i,0,0),fws);
    kA_ffn<<<INST_MAX,256,0,stream>>>(f1w(i,0),f1b(i,0),f2w(i,0),f2b(i,0),lng(i,0,1),lnb(i,0,1),fws);
    kA_kv<<<1,256,0,stream>>>(aw(i,1,1),ab(i,1,1),aw(i,1,2),ab(i,1,2),fws);
    // ---- scene-side layer (queries = scene, keys/vals = instances) ----
    kQ<<<NB64,256,0,stream>>>(A1,aw(i,1,0),ab(i,1,0),SE,fidx,posw,vorigin,fws);
    kAttnOLN<<<NB64,256,0,stream>>>(A1,A2,aw(i,1,3),ab(i,1,3),lng(i,1,0),lnb(i,1,0),SE,fidx,posw,vorigin,fws);
    k_transpose<<<dim3(4,16),dim3(32,8),0,stream>>>(f1w(i,1),W1T,512,128);
    k_transpose<<<dim3(16,4),dim3(32,8),0,stream>>>(f2w(i,1),W2T,128,512);
    kFFN<<<NB64,256,0,stream>>>(A2,SE,W1T,W2T,f1b(i,1),f2b(i,1),lng(i,1,1),lnb(i,1,1),fws);
  }
  k_out<<<NQ/64,256,0,stream>>>(SE,sew,x3d,convw,convb,invr,out,fws);
}

// Round 7
// 2439.375 us; speedup vs baseline: 1.0686x; 1.0523x over previous
//
#include <hip/hip_runtime.h>
#include <math.h>

#define EMBED 128
#define NCLS 21
#define NI_ 300
#define IMH 96
#define IMW 320
#define NPIX (IMH*IMW)
#define NQ 262144
#define NF_MAX 73728
#define INST_MAX 16
#define IH_MAX 64
#define RS32 0.17677669529663687f

// ---- SMALL region layout (4-byte units at ws base) ----
#define S_NF 0
#define S_NK 1
#define S_NINST 2
#define S_NIH 3
#define S_INVK 8      // 9 f
#define S_INVE 24     // 16 f
#define S_KIDX 64     // 300 i
#define S_SKK 400     // 300 f
#define S_MAREA 768   // 300 i
#define S_PAREA 1088  // 300 i
#define S_AREA2 1408  // 300 i
#define S_XYZ 1728    // 900 f
#define S_SELJ 2656   // 16 i
#define S_K2 2688     // 16 i
#define S_FCNT 3072   // 256 i
#define S_FOFF 3328   // 256 i
#define S_INSTQ 4096  // 16*128 f
#define S_INSTP 6144
#define S_QIN 8192
#define S_QH 10240
#define S_XI 12288
#define S_KHB 16384
#define S_VHB 18432
#define S_QKT 20480   // 64*128 f
#define S_SB 28672    // 64 f
#define S_SUMV 28928  // 64 f
#define S_WSUM 29056  // 64*128 f

#define OFF_FIDX ((size_t)1<<20)
#define OFF_INV  ((size_t)2<<20)
#define OFF_W1T  ((size_t)3<<20)
#define OFF_SE   ((size_t)4<<20)
#define SE_BYTES ((size_t)NF_MAX*128*4)
#define OFF_A1   (OFF_SE + SE_BYTES)
#define OFF_A2   (OFF_A1 + SE_BYTES)
#define OFF_SC   (OFF_A2 + SE_BYTES)

__global__ __launch_bounds__(256) void k_init(const float* Km, const float* Em, float* ws){
  int* iw = (int*)ws;
  for (int i = threadIdx.x; i < 4096; i += 256) iw[i] = 0;
  __syncthreads();
  if (threadIdx.x == 0){
    float* fw = ws;
    const float* K = Km;
    float A = K[4]*K[8]-K[5]*K[7];
    float B = K[5]*K[6]-K[3]*K[8];
    float C = K[3]*K[7]-K[4]*K[6];
    float det = K[0]*A + K[1]*B + K[2]*C;
    float id = 1.0f/det;
    fw[S_INVK+0] = A*id;
    fw[S_INVK+1] = (K[2]*K[7]-K[1]*K[8])*id;
    fw[S_INVK+2] = (K[1]*K[5]-K[2]*K[4])*id;
    fw[S_INVK+3] = B*id;
    fw[S_INVK+4] = (K[0]*K[8]-K[2]*K[6])*id;
    fw[S_INVK+5] = (K[2]*K[3]-K[0]*K[5])*id;
    fw[S_INVK+6] = C*id;
    fw[S_INVK+7] = (K[1]*K[6]-K[0]*K[7])*id;
    fw[S_INVK+8] = (K[0]*K[4]-K[1]*K[3])*id;
    // 4x4 Gauss-Jordan inverse of E
    float M[4][8];
    for (int r=0;r<4;r++){ for(int c=0;c<4;c++){ M[r][c]=Em[r*4+c]; M[r][4+c]=(r==c)?1.f:0.f; } }
    for (int col=0; col<4; col++){
      int piv=col; float best=fabsf(M[col][col]);
      for (int r=col+1;r<4;r++){ float v=fabsf(M[r][col]); if(v>best){best=v;piv=r;} }
      if (piv!=col){ for(int c=0;c<8;c++){ float tmp=M[col][c]; M[col][c]=M[piv][c]; M[piv][c]=tmp; } }
      float inv=1.0f/M[col][col];
      for (int c=0;c<8;c++) M[col][c]*=inv;
      for (int r=0;r<4;r++){ if(r==col) continue; float f=M[r][col]; for(int c=0;c<8;c++) M[r][c]-=f*M[col][c]; }
    }
    for (int r=0;r<4;r++) for(int c=0;c<4;c++) fw[S_INVE+r*4+c]=M[r][4+c];
  }
}

__global__ __launch_bounds__(320) void k_score(const float* logits, float* ws){
  int* iw=(int*)ws; float* fw=ws;
  __shared__ float ssc[NI_];
  __shared__ int skp[NI_];
  int t=threadIdx.x;
  if (t < NI_){
    float v[NCLS]; float mx=-1e30f;
    for (int c=0;c<NCLS;c++){
      float l=logits[t*NCLS+c];
      float sg=1.0f/(1.0f+expf(-l));
      float x=sg/0.06f;
      v[c]=x; mx=fmaxf(mx,x);
    }
    float s=0.f;
    for (int c=0;c<NCLS;c++) s += expf(v[c]-mx);
    float score=1.0f/s;     // max softmax prob
    ssc[t]=score; skp[t]=(score>0.25f)?1:0;
  }
  __syncthreads();
  if (t==0){
    int nk=0;
    for (int i=0;i<NI_;i++){ if(skp[i]){ iw[S_KIDX+nk]=i; fw[S_SKK+nk]=ssc[i]; nk++; } }
    iw[S_NK]=nk;
  }
}

// Block-level pre-reduction: per-query partial counts/sums in LDS, then
// at most nk*6 global atomics per block.
__global__ __launch_bounds__(256) void k_winner(const float* pmask, const float* depth, float* ws){
  int* iw=(int*)ws; float* fw=ws;
  int nk=iw[S_NK];
  if (nk>NI_) nk=NI_;
  __shared__ int s_pa[NI_], s_ma[NI_], s_a2[NI_];
  __shared__ float s_x[NI_], s_y[NI_], s_z[NI_];
  __shared__ int s_gi[NI_];
  __shared__ float s_sc[NI_];
  int t=threadIdx.x;
  int lane=t&63;
  for (int j=t;j<nk;j+=256){
    s_pa[j]=0; s_ma[j]=0; s_a2[j]=0;
    s_x[j]=0.f; s_y[j]=0.f; s_z[j]=0.f;
    s_gi[j]=iw[S_KIDX+j]; s_sc[j]=fw[S_SKK+j];
  }
  __syncthreads();
  int p=blockIdx.x*256+t;
  float best=-1e30f; int jw=-1; float mw=0.f;
  for (int j=0;j<nk;j++){
    float m=1.0f/(1.0f+expf(-pmask[(size_t)s_gi[j]*NPIX+p]));
    unsigned long long msk=__ballot(m>=0.5f);
    if (lane==0 && msk) atomicAdd(&s_pa[j], __popcll(msk));
    float wv=s_sc[j]*m;
    if (wv>best){ best=wv; jw=j; mw=m; }
  }
  if (jw>=0){
    atomicAdd(&s_ma[jw],1);
    if (mw>=0.5f){
      atomicAdd(&s_a2[jw],1);
      float d=depth[p];
      float gx=(float)(p%IMW)*4.0f, gy=(float)(p/IMW)*4.0f;
      float X=gx*d, Y=gy*d;
      const float* iK=fw+S_INVK; const float* iE=fw+S_INVE;
      float c0=iK[0]*X+iK[1]*Y+iK[2]*d;
      float c1=iK[3]*X+iK[4]*Y+iK[5]*d;
      float c2=iK[6]*X+iK[7]*Y+iK[8]*d;
      float wx=iE[0]*c0+iE[1]*c1+iE[2]*c2+iE[3];
      float wy=iE[4]*c0+iE[5]*c1+iE[6]*c2+iE[7];
      float wz=iE[8]*c0+iE[9]*c1+iE[10]*c2+iE[11];
      atomicAdd(&s_x[jw],wx);
      atomicAdd(&s_y[jw],wy);
      atomicAdd(&s_z[jw],wz);
    }
  }
  __syncthreads();
  for (int j=t;j<nk;j+=256){
    if (s_pa[j]) atomicAdd(&iw[S_PAREA+j],s_pa[j]);
    if (s_ma[j]) atomicAdd(&iw[S_MAREA+j],s_ma[j]);
    if (s_a2[j]) atomicAdd(&iw[S_AREA2+j],s_a2[j]);
    if (s_x[j]!=0.f) atomicAdd(&fw[S_XYZ+j*3+0],s_x[j]);
    if (s_y[j]!=0.f) atomicAdd(&fw[S_XYZ+j*3+1],s_y[j]);
    if (s_z[j]!=0.f) atomicAdd(&fw[S_XYZ+j*3+2],s_z[j]);
  }
}

__global__ __launch_bounds__(256) void k_sel(const float* queries, const float* instposw, const float* posw, float* ws){
  int* iw=(int*)ws; float* fw=ws;
  __shared__ int sn;
  if (threadIdx.x==0){
    int nk=iw[S_NK]; int n=0;
    for (int j=0;j<nk;j++){
      int a2=iw[S_AREA2+j];
      if (a2>0){
        float r=(float)iw[S_MAREA+j]/(float)iw[S_PAREA+j];
        if (r>=0.8f && n<INST_MAX){ iw[S_SELJ+n]=j; iw[S_K2+n]=iw[S_KIDX+j]; n++; }
      }
    }
    iw[S_NINST]=n; iw[S_NIH]=4*n; sn=n;
  }
  __syncthreads();
  int n=sn;
  for (int idx=threadIdx.x; idx<n*128; idx+=256){
    int i=idx>>7, e=idx&127;
    int j=iw[S_SELJ+i]; int gi=iw[S_K2+i];
    fw[S_INSTQ+idx]=queries[gi*128+e];
    float mp=fw[S_XYZ+j*3]*posw[e*3]+fw[S_XYZ+j*3+1]*posw[e*3+1]+fw[S_XYZ+j*3+2]*posw[e*3+2];
    fw[S_INSTP+idx]=instposw[gi*128+e]+mp;
  }
}

__global__ __launch_bounds__(256) void k_fov_count(const int* fov, float* ws){
  int* iw=(int*)ws;
  __shared__ int red[256];
  int t=threadIdx.x;
  int base=blockIdx.x*1024;
  int s=0;
  for (int k=0;k<4;k++) s += (fov[base+k*256+t]!=0)?1:0;
  red[t]=s; __syncthreads();
  for (int st=128;st>0;st>>=1){ if(t<st) red[t]+=red[t+st]; __syncthreads(); }
  if (t==0) iw[S_FCNT+blockIdx.x]=red[0];
}

__global__ void k_fov_scan(float* ws){
  int* iw=(int*)ws;
  if (threadIdx.x==0){
    int acc=0;
    for (int b=0;b<256;b++){ iw[S_FOFF+b]=acc; acc+=iw[S_FCNT+b]; }
    iw[S_NF]=(acc<NF_MAX)?acc:NF_MAX;
  }
}

__global__ __launch_bounds__(256) void k_fov_scatter(const int* fov, float* ws){
  int* iw=(int*)ws;
  int* fidx=(int*)((char*)ws+OFF_FIDX);
  int* invr=(int*)((char*)ws+OFF_INV);
  __shared__ int wsums[4];
  __shared__ int woff[4];
  __shared__ int cur;
  __shared__ int tot;
  int t=threadIdx.x; int w=t>>6; int lane=t&63;
  if (t==0) cur=iw[S_FOFF+blockIdx.x];
  __syncthreads();
  int base=blockIdx.x*1024;
  for (int k=0;k<4;k++){
    int i=base+k*256+t;
    int f=(fov[i]!=0)?1:0;
    unsigned long long m=__ballot(f);
    int rk=__popcll(m & ((lane==0)?0ull:((~0ull)>>(64-lane))));
    if (lane==0) wsums[w]=__popcll(m);
    __syncthreads();
    if (t==0){ int a=0; for(int q2=0;q2<4;q2++){ woff[q2]=a; a+=wsums[q2]; } tot=a; }
    __syncthreads();
    if (f){
      int r=cur+woff[w]+rk;
      if (r<NF_MAX){ fidx[r]=i; invr[i]=r; } else invr[i]=-1;
    } else invr[i]=-1;
    __syncthreads();
    if (t==0) cur+=tot;
    __syncthreads();
  }
}

__global__ __launch_bounds__(256) void k_se_build(const float* sew, const float* x3d, const int* fidx, float* SE, float* ws){
  int* iw=(int*)ws;
  int nf=iw[S_NF];
  int r0=blockIdx.x*64;
  if (r0>=nf) return;
  int nr=min(64,nf-r0);
  __shared__ float tile[64][129];
  __shared__ int fidxl[64];
  int t=threadIdx.x;
  if (t<64) fidxl[t]=(t<nr)? fidx[r0+t]:0;
  __syncthreads();
  for (int idx=t; idx<64*128; idx+=256){
    int v=idx>>7, e=idx&127;
    tile[v][e]=(v<nr)? sew[(size_t)fidxl[v]*128+e]:0.f;
  }
  __syncthreads();
  for (int idx=t; idx<128*64; idx+=256){
    int c=idx>>6, v=idx&63;
    if (v<nr) tile[v][c]+=x3d[(size_t)c*NQ+fidxl[v]];
  }
  __syncthreads();
  for (int idx=t; idx<64*128; idx+=256){
    int v=idx>>7, e=idx&127;
    if (v<nr) SE[(r0+v)*128+e]=tile[v][e];
  }
}

// kA_prep v2: multi-block. Every block redundantly computes QIN+QH (tiny) in
// LDS with per-thread-contiguous float4 W reads; block b owns QKT row ih=b.
// Replaces the 1-block, 1-CU, scalar-uncoalesced version (latency-bound).
__global__ __launch_bounds__(256) void kA_prep(const float* __restrict__ Wq, const float* __restrict__ bq,
    const float* __restrict__ Wk, const float* __restrict__ bk, float* __restrict__ ws){
  int* iw=(int*)ws; float* fw=ws;
  int n=iw[S_NINST]; int nih=iw[S_NIH];
  int b=blockIdx.x;
  if (b>=nih) return;
  int t=threadIdx.x;
  __shared__ __attribute__((aligned(16))) float qin[INST_MAX*128];
  __shared__ __attribute__((aligned(16))) float qh[INST_MAX*128];
  for (int idx=t; idx<n*128; idx+=256)
    qin[idx]=fw[S_INSTQ+idx]+fw[S_INSTP+idx];
  __syncthreads();
  for (int idx=t; idx<n*128; idx+=256){
    int i=idx>>7, e=idx&127;
    float a=bq[e];
    const float4* wr=reinterpret_cast<const float4*>(Wq+(size_t)e*128);
    const float4* xr=reinterpret_cast<const float4*>(qin+i*128);
    #pragma unroll 8
    for (int k4=0;k4<32;k4++){
      float4 w=wr[k4]; float4 x=xr[k4];
      a+=x.x*w.x+x.y*w.y+x.z*w.z+x.w*w.w;
    }
    qh[idx]=a;
  }
  __syncthreads();
  int i=b>>2, h=b&3;
  const float* qs=qh+i*128+h*32;
  if (t<128){
    float a=0.f;
    #pragma unroll 8
    for (int d=0;d<32;d++) a+=qs[d]*Wk[(size_t)(h*32+d)*128+t];
    fw[S_QKT+b*128+t]=a*RS32;
  } else if (t==128){
    float a=0.f;
    for (int d=0;d<32;d++) a+=qs[d]*bk[h*32+d];
    fw[S_SB+b]=a*RS32;
  }
}

// kS1 v2: SC[ih][r] = sb[ih] + qk[ih][:] . xt[r][:]  register-tiled 64x64x128.
__global__ __launch_bounds__(256) void kS1(const float* SE, float* SC, const float* posw, const float* org, const int* fidx, float* ws){
  int* iw=(int*)ws; float* fw=ws;
  int nf=iw[S_NF]; int nih=iw[S_NIH];
  int r0=blockIdx.x*64;
  if (r0>=nf || nih==0) return;
  int nr=min(64,nf-r0);
  __shared__ float xt[64][132];
  __shared__ float qk[64][132];
  __shared__ float sbl[64];
  __shared__ float pwl[384];
  __shared__ float px[64],py[64],pz[64];
  __shared__ int fidxl[64];
  int t=threadIdx.x;
  for (int i=t;i<384;i+=256) pwl[i]=posw[i];
  if (t<64) fidxl[t]=(t<nr)? fidx[r0+t]:0;
  for (int idx=t; idx<64*32; idx+=256){
    int ih=idx>>5, e4=(idx&31)*4;
    float4 v = (ih<nih)? *reinterpret_cast<const float4*>(&fw[S_QKT+ih*128+e4])
                       : make_float4(0.f,0.f,0.f,0.f);
    *reinterpret_cast<float4*>(&qk[ih][e4]) = v;
  }
  if (t<64) sbl[t]=(t<nih)? fw[S_SB+t]:0.f;
  __syncthreads();
  if (t<64){
    int q=fidxl[t];
    int vx=q>>11, vy=(q>>4)&127, vz=q&15;
    px[t]=(vx+0.5f)*0.2f+org[0];
    py[t]=(vy+0.5f)*0.2f+org[1];
    pz[t]=(vz+0.5f)*0.2f+org[2];
  }
  __syncthreads();
  for (int idx=t; idx<64*32; idx+=256){
    int v=idx>>5, e4=(idx&31)*4;
    float4 s=make_float4(0.f,0.f,0.f,0.f);
    if (v<nr){
      s=*reinterpret_cast<const float4*>(SE+(size_t)(r0+v)*128+e4);
      float X=px[v], Y=py[v], Z=pz[v];
      s.x+=X*pwl[(e4+0)*3]+Y*pwl[(e4+0)*3+1]+Z*pwl[(e4+0)*3+2];
      s.y+=X*pwl[(e4+1)*3]+Y*pwl[(e4+1)*3+1]+Z*pwl[(e4+1)*3+2];
      s.z+=X*pwl[(e4+2)*3]+Y*pwl[(e4+2)*3+1]+Z*pwl[(e4+2)*3+2];
      s.w+=X*pwl[(e4+3)*3]+Y*pwl[(e4+3)*3+1]+Z*pwl[(e4+3)*3+2];
    }
    *reinterpret_cast<float4*>(&xt[v][e4])=s;
  }
  __syncthreads();
  int tx=t&15, ty=t>>4;
  int ih0=ty*4;
  float acc[4][4];
  #pragma unroll
  for (int i=0;i<4;i++)
    #pragma unroll
    for (int j=0;j<4;j++) acc[i][j]=0.f;
  for (int k=0;k<128;k+=4){
    float4 q0=*reinterpret_cast<const float4*>(&qk[ih0+0][k]);
    float4 q1=*reinterpret_cast<const float4*>(&qk[ih0+1][k]);
    float4 q2=*reinterpret_cast<const float4*>(&qk[ih0+2][k]);
    float4 q3=*reinterpret_cast<const float4*>(&qk[ih0+3][k]);
    #pragma unroll
    for (int j=0;j<4;j++){
      float4 x=*reinterpret_cast<const float4*>(&xt[tx+16*j][k]);
      acc[0][j]+=q0.x*x.x+q0.y*x.y+q0.z*x.z+q0.w*x.w;
      acc[1][j]+=q1.x*x.x+q1.y*x.y+q1.z*x.z+q1.w*x.w;
      acc[2][j]+=q2.x*x.x+q2.y*x.y+q2.z*x.z+q2.w*x.w;
      acc[3][j]+=q3.x*x.x+q3.y*x.y+q3.z*x.z+q3.w*x.w;
    }
  }
  #pragma unroll
  for (int i=0;i<4;i++){
    int ih=ih0+i;
    if (ih>=nih) break;
    float sb=sbl[ih];
    #pragma unroll
    for (int j=0;j<4;j++){
      int tok=tx+16*j;
      if (tok<nr) SC[(size_t)ih*NF_MAX+r0+tok]=acc[i][j]+sb;
    }
  }
}

__global__ __launch_bounds__(256) void kS2S3(float* SC, float* ws){
  int* iw=(int*)ws; float* fw=ws;
  int nih=iw[S_NIH]; int ih=blockIdx.x;
  if (ih>=nih) return;
  int nf=iw[S_NF];
  float* row=SC+(size_t)ih*NF_MAX;
  __shared__ float red[256];
  int t=threadIdx.x;
  float m=-1e30f;
  for (int j=t;j<nf;j+=256) m=fmaxf(m,row[j]);
  red[t]=m; __syncthreads();
  for (int s=128;s>0;s>>=1){ if(t<s) red[t]=fmaxf(red[t],red[t+s]); __syncthreads(); }
  m=red[0]; __syncthreads();
  float sum=0.f;
  for (int j=t;j<nf;j+=256){ float p=expf(row[j]-m); row[j]=p; sum+=p; }
  red[t]=sum; __syncthreads();
  for (int s=128;s>0;s>>=1){ if(t<s) red[t]+=red[t+s]; __syncthreads(); }
  if (t==0) fw[S_SUMV+ih]=red[0];
  if (t<128) fw[S_WSUM+ih*128+t]=0.f;
}

// kS4 v2: direct global/L1 reads, no LDS, 4x8 register accumulator.
__global__ __launch_bounds__(256) void kS4(const float* __restrict__ SC, const float* __restrict__ SE, float* __restrict__ ws){
  int* iw=(int*)ws; float* fw=ws;
  int nf=iw[S_NF]; int nih=iw[S_NIH];
  if (nih==0) return;
  int t=threadIdx.x;
  int chunk=(nf+255)/256;
  int j0=blockIdx.x*chunk;
  int j1=min(nf,j0+chunk);
  if (j0>=j1) return;
  int tx=t&15, ty=t>>4;
  int ecol=tx*8, ih0=ty*4;
  const float* sc0=SC+(size_t)(ih0+0)*NF_MAX;
  const float* sc1=SC+(size_t)(ih0+1)*NF_MAX;
  const float* sc2=SC+(size_t)(ih0+2)*NF_MAX;
  const float* sc3=SC+(size_t)(ih0+3)*NF_MAX;
  bool g0=ih0+0<nih, g1=ih0+1<nih, g2=ih0+2<nih, g3=ih0+3<nih;
  float acc[4][8];
  #pragma unroll
  for (int i=0;i<4;i++)
    #pragma unroll
    for (int j=0;j<8;j++) acc[i][j]=0.f;
  #pragma unroll 4
  for (int j=j0;j<j1;j++){
    float4 sa=*reinterpret_cast<const float4*>(SE+(size_t)j*128+ecol);
    float4 sb=*reinterpret_cast<const float4*>(SE+(size_t)j*128+ecol+4);
    float s0=g0? sc0[j]:0.f;
    float s1=g1? sc1[j]:0.f;
    float s2=g2? sc2[j]:0.f;
    float s3=g3? sc3[j]:0.f;
    acc[0][0]+=s0*sa.x; acc[0][1]+=s0*sa.y; acc[0][2]+=s0*sa.z; acc[0][3]+=s0*sa.w;
    acc[0][4]+=s0*sb.x; acc[0][5]+=s0*sb.y; acc[0][6]+=s0*sb.z; acc[0][7]+=s0*sb.w;
    acc[1][0]+=s1*sa.x; acc[1][1]+=s1*sa.y; acc[1][2]+=s1*sa.z; acc[1][3]+=s1*sa.w;
    acc[1][4]+=s1*sb.x; acc[1][5]+=s1*sb.y; acc[1][6]+=s1*sb.z; acc[1][7]+=s1*sb.w;
    acc[2][0]+=s2*sa.x; acc[2][1]+=s2*sa.y; acc[2][2]+=s2*sa.z; acc[2][3]+=s2*sa.w;
    acc[2][4]+=s2*sb.x; acc[2][5]+=s2*sb.y; acc[2][6]+=s2*sb.z; acc[2][7]+=s2*sb.w;
    acc[3][0]+=s3*sa.x; acc[3][1]+=s3*sa.y; acc[3][2]+=s3*sa.z; acc[3][3]+=s3*sa.w;
    acc[3][4]+=s3*sb.x; acc[3][5]+=s3*sb.y; acc[3][6]+=s3*sb.z; acc[3][7]+=s3*sb.w;
  }
  #pragma unroll
  for (int i=0;i<4;i++){
    int ih=ih0+i;
    if (ih>=nih) break;
    #pragma unroll
    for (int jj=0;jj<8;jj++)
      atomicAdd(&fw[S_WSUM+ih*128+ecol+jj], acc[i][jj]);
  }
}

// kA_tail: fuses kA_post + kA_ffn + kA_kv, one block per instance. All weight
// loops are per-thread-contiguous float4 (L1-friendly); everything in LDS.
// De-serializes the former 1-block chain across n CUs and cuts 2 dispatches.
__global__ __launch_bounds__(256) void kA_tail(
    const float* __restrict__ Wv, const float* __restrict__ bv,
    const float* __restrict__ Wo, const float* __restrict__ bo,
    const float* __restrict__ g0, const float* __restrict__ bb0,
    const float* __restrict__ W1, const float* __restrict__ b1,
    const float* __restrict__ W2, const float* __restrict__ b2,
    const float* __restrict__ g1, const float* __restrict__ bb1,
    const float* __restrict__ Wk2, const float* __restrict__ bk2,
    const float* __restrict__ Wv2, const float* __restrict__ bv2,
    float* __restrict__ ws){
  int* iw=(int*)ws; float* fw=ws;
  int n=iw[S_NINST];
  int i=blockIdx.x;
  if (i>=n) return;
  int t=threadIdx.x;
  __shared__ __attribute__((aligned(16))) float wn4[4*128];
  __shared__ __attribute__((aligned(16))) float ol[128];
  __shared__ __attribute__((aligned(16))) float xi[128];
  __shared__ __attribute__((aligned(16))) float hid[512];
  __shared__ __attribute__((aligned(16))) float qrow[128];
  __shared__ __attribute__((aligned(16))) float prow[128];
  for (int idx=t; idx<512; idx+=256){
    int ih=i*4+(idx>>7);
    wn4[idx]=fw[S_WSUM+ih*128+(idx&127)]/fw[S_SUMV+ih];
  }
  if (t<128) prow[t]=fw[S_INSTP+i*128+t];
  __syncthreads();
  // V-proj: ol[f] = bv[f] + Wv[f,:] . wn4[f>>5]
  if (t<128){
    int h=t>>5;
    float a=bv[t];
    const float4* wr=reinterpret_cast<const float4*>(Wv+(size_t)t*128);
    const float4* xr=reinterpret_cast<const float4*>(wn4+h*128);
    #pragma unroll 8
    for (int k4=0;k4<32;k4++){
      float4 w=wr[k4]; float4 x=xr[k4];
      a+=x.x*w.x+x.y*w.y+x.z*w.z+x.w*w.w;
    }
    ol[t]=a;
  }
  __syncthreads();
  // O-proj + residual(old QIN): xi[e] (pre-LN)
  if (t<128){
    float a=bo[t];
    const float4* wr=reinterpret_cast<const float4*>(Wo+(size_t)t*128);
    const float4* xr=reinterpret_cast<const float4*>(ol);
    #pragma unroll 8
    for (int k4=0;k4<32;k4++){
      float4 w=wr[k4]; float4 x=xr[k4];
      a+=x.x*w.x+x.y*w.y+x.z*w.z+x.w*w.w;
    }
    xi[t]=a+fw[S_INSTQ+i*128+t]+prow[t];
  }
  __syncthreads();
  if (t<64){
    float v0=xi[t], v1=xi[t+64];
    float s=v0+v1;
    for (int o=32;o>0;o>>=1) s+=__shfl_xor(s,o);
    float mu=s*(1.f/128.f);
    float d0=v0-mu, d1=v1-mu;
    float vv=d0*d0+d1*d1;
    for (int o=32;o>0;o>>=1) vv+=__shfl_xor(vv,o);
    float rsv=rsqrtf(vv*(1.f/128.f)+1e-5f);
    xi[t]=d0*rsv*g0[t]+bb0[t];
    xi[t+64]=d1*rsv*g0[t+64]+bb0[t+64];
  }
  __syncthreads();
  // FFN up
  for (int d=t; d<512; d+=256){
    float a=b1[d];
    const float4* wr=reinterpret_cast<const float4*>(W1+(size_t)d*128);
    const float4* xr=reinterpret_cast<const float4*>(xi);
    #pragma unroll 8
    for (int k4=0;k4<32;k4++){
      float4 w=wr[k4]; float4 x=xr[k4];
      a+=x.x*w.x+x.y*w.y+x.z*w.z+x.w*w.w;
    }
    hid[d]=fmaxf(a,0.f);
  }
  __syncthreads();
  // FFN down + residual
  if (t<128){
    float a=b2[t];
    const float4* wr=reinterpret_cast<const float4*>(W2+(size_t)t*512);
    const float4* xr=reinterpret_cast<const float4*>(hid);
    #pragma unroll 8
    for (int k4=0;k4<128;k4++){
      float4 w=wr[k4]; float4 x=xr[k4];
      a+=x.x*w.x+x.y*w.y+x.z*w.z+x.w*w.w;
    }
    qrow[t]=a+xi[t];
  }
  __syncthreads();
  if (t<64){
    float v0=qrow[t], v1=qrow[t+64];
    float s=v0+v1;
    for (int o=32;o>0;o>>=1) s+=__shfl_xor(s,o);
    float mu=s*(1.f/128.f);
    float d0=v0-mu, d1=v1-mu;
    float vv=d0*d0+d1*d1;
    for (int o=32;o>0;o>>=1) vv+=__shfl_xor(vv,o);
    float rsv=rsqrtf(vv*(1.f/128.f)+1e-5f);
    qrow[t]=d0*rsv*g1[t]+bb1[t];
    qrow[t+64]=d1*rsv*g1[t+64]+bb1[t+64];
  }
  __syncthreads();
  if (t<128) fw[S_INSTQ+i*128+t]=qrow[t];
  {
    int e=t&127, which=t>>7;
    if (which==0){
      float a=bk2[e];
      const float4* wr=reinterpret_cast<const float4*>(Wk2+(size_t)e*128);
      #pragma unroll 8
      for (int k4=0;k4<32;k4++){
        float4 w=wr[k4];
        float4 q4=*reinterpret_cast<const float4*>(qrow+k4*4);
        float4 p4=*reinterpret_cast<const float4*>(prow+k4*4);
        a+=(q4.x+p4.x)*w.x+(q4.y+p4.y)*w.y+(q4.z+p4.z)*w.z+(q4.w+p4.w)*w.w;
      }
      fw[S_KHB+i*128+e]=a;
    } else {
      float a=bv2[e];
      const float4* wr=reinterpret_cast<const float4*>(Wv2+(size_t)e*128);
      #pragma unroll 8
      for (int k4=0;k4<32;k4++){
        float4 w=wr[k4];
        float4 q4=*reinterpret_cast<const float4*>(qrow+k4*4);
        a+=q4.x*w.x+q4.y*w.y+q4.z*w.z+q4.w*w.w;
      }
      fw[S_VHB+i*128+e]=a;
    }
  }
}

// kQ: scene-side q-projection. A1[r][e] = (SE[r]+pos(r)) . Wq[e][:] + bq[e].
__global__ __launch_bounds__(256) void kQ(float* __restrict__ A1,
    const float* __restrict__ Wq, const float* __restrict__ bq,
    const float* __restrict__ SE, const int* __restrict__ fidx,
    const float* __restrict__ posw, const float* __restrict__ org, float* __restrict__ ws){
  int* iw=(int*)ws;
  int nf=iw[S_NF];
  int r0=blockIdx.x*64;
  if (r0>=nf) return;
  __shared__ float Xs[64][132];
  __shared__ float pwl[384];
  __shared__ float px[64],py[64],pz[64];
  int t=threadIdx.x;
  for (int i=t;i<384;i+=256) pwl[i]=posw[i];
  if (t<64){
    int r=r0+t;
    int q=(r<nf)? fidx[r]:0;
    int vx=q>>11, vy=(q>>4)&127, vz=q&15;
    px[t]=(vx+0.5f)*0.2f+org[0];
    py[t]=(vy+0.5f)*0.2f+org[1];
    pz[t]=(vz+0.5f)*0.2f+org[2];
  }
  __syncthreads();
  for (int idx=t; idx<64*32; idx+=256){
    int rl=idx>>5, e4=(idx&31)*4;
    float4 v=*reinterpret_cast<const float4*>(SE+(size_t)(r0+rl)*128+e4);
    float X=px[rl], Y=py[rl], Z=pz[rl];
    v.x+=X*pwl[(e4+0)*3]+Y*pwl[(e4+0)*3+1]+Z*pwl[(e4+0)*3+2];
    v.y+=X*pwl[(e4+1)*3]+Y*pwl[(e4+1)*3+1]+Z*pwl[(e4+1)*3+2];
    v.z+=X*pwl[(e4+2)*3]+Y*pwl[(e4+2)*3+1]+Z*pwl[(e4+2)*3+2];
    v.w+=X*pwl[(e4+3)*3]+Y*pwl[(e4+3)*3+1]+Z*pwl[(e4+3)*3+2];
    *reinterpret_cast<float4*>(&Xs[rl][e4])=v;
  }
  __syncthreads();
  int tx=t&15, ty=t>>4, ty4=ty*4, ecol=tx*8;
  float acc[4][8];
  #pragma unroll
  for (int i=0;i<4;i++)
    #pragma unroll
    for (int j=0;j<8;j++) acc[i][j]=0.f;
  for (int k=0;k<128;k+=4){
    float4 xv0=*reinterpret_cast<const float4*>(&Xs[ty4+0][k]);
    float4 xv1=*reinterpret_cast<const float4*>(&Xs[ty4+1][k]);
    float4 xv2=*reinterpret_cast<const float4*>(&Xs[ty4+2][k]);
    float4 xv3=*reinterpret_cast<const float4*>(&Xs[ty4+3][k]);
    #pragma unroll
    for (int jj=0;jj<8;jj++){
      float4 w=*reinterpret_cast<const float4*>(Wq+(size_t)(ecol+jj)*128+k);
      acc[0][jj]+=xv0.x*w.x+xv0.y*w.y+xv0.z*w.z+xv0.w*w.w;
      acc[1][jj]+=xv1.x*w.x+xv1.y*w.y+xv1.z*w.z+xv1.w*w.w;
      acc[2][jj]+=xv2.x*w.x+xv2.y*w.y+xv2.z*w.z+xv2.w*w.w;
      acc[3][jj]+=xv3.x*w.x+xv3.y*w.y+xv3.z*w.z+xv3.w*w.w;
    }
  }
  float4 bqa=*reinterpret_cast<const float4*>(bq+ecol);
  float4 bqb=*reinterpret_cast<const float4*>(bq+ecol+4);
  #pragma unroll
  for (int i=0;i<4;i++){
    int r=r0+ty4+i;
    if (r>=nf) continue;
    float4 o1, o2;
    o1.x=acc[i][0]+bqa.x; o1.y=acc[i][1]+bqa.y; o1.z=acc[i][2]+bqa.z; o1.w=acc[i][3]+bqa.w;
    o2.x=acc[i][4]+bqb.x; o2.y=acc[i][5]+bqb.y; o2.z=acc[i][6]+bqb.z; o2.w=acc[i][7]+bqb.w;
    *reinterpret_cast<float4*>(A1+(size_t)r*128+ecol)=o1;
    *reinterpret_cast<float4*>(A1+(size_t)r*128+ecol+4)=o2;
  }
}

// kAttnOLN: fuses 16-key attention + o-projection + residual(SE+pos) + LN.
__global__ __launch_bounds__(256) void kAttnOLN(const float* __restrict__ A1, float* __restrict__ A2,
    const float* __restrict__ Wo, const float* __restrict__ bo,
    const float* __restrict__ g, const float* __restrict__ bb,
    const float* __restrict__ SE, const int* __restrict__ fidx,
    const float* __restrict__ posw, const float* __restrict__ org, float* __restrict__ ws){
  int* iw=(int*)ws; float* fw=ws;
  int nf=iw[S_NF]; int n=iw[S_NINST];
  int r0=blockIdx.x*64;
  if (r0>=nf) return;
  __shared__ float ot[64][132];
  __shared__ float kh[INST_MAX*128];
  __shared__ float vh[INST_MAX*128];
  __shared__ float pwl[384];
  __shared__ float px[64],py[64],pz[64];
  int t=threadIdx.x;
  for (int idx=t; idx<INST_MAX*128; idx+=256){
    kh[idx]=(idx<n*128)? fw[S_KHB+idx]:0.f;
    vh[idx]=(idx<n*128)? fw[S_VHB+idx]:0.f;
  }
  for (int i=t;i<384;i+=256) pwl[i]=posw[i];
  if (t<64){
    int r=r0+t;
    int q=(r<nf)? fidx[r]:0;
    int vx=q>>11, vy=(q>>4)&127, vz=q&15;
    px[t]=(vx+0.5f)*0.2f+org[0];
    py[t]=(vy+0.5f)*0.2f+org[1];
    pz[t]=(vz+0.5f)*0.2f+org[2];
  }
  for (int idx=t; idx<64*32; idx+=256){
    int rl=idx>>5, e4=(idx&31)*4;
    *reinterpret_cast<float4*>(&ot[rl][e4]) =
      *reinterpret_cast<const float4*>(A1+(size_t)(r0+rl)*128+e4);
  }
  __syncthreads();
  {
    int tokl=t&63, h=t>>6;
    float q[32];
    #pragma unroll
    for (int d8=0;d8<8;d8++){
      float4 v=*reinterpret_cast<const float4*>(&ot[tokl][h*32+d8*4]);
      q[d8*4]=v.x; q[d8*4+1]=v.y; q[d8*4+2]=v.z; q[d8*4+3]=v.w;
    }
    float s[INST_MAX]; float mx=-1e30f;
    for (int j=0;j<INST_MAX;j++){
      float a=0.f;
      #pragma unroll
      for (int d4=0;d4<8;d4++){
        float4 kv=*reinterpret_cast<const float4*>(&kh[j*128+h*32+d4*4]);
        a+=q[d4*4]*kv.x+q[d4*4+1]*kv.y+q[d4*4+2]*kv.z+q[d4*4+3]*kv.w;
      }
      a*=RS32;
      s[j]=(j<n)? a:-1e30f;
      mx=fmaxf(mx,s[j]);
    }
    float sum=0.f;
    for (int j=0;j<INST_MAX;j++){ float p=expf(s[j]-mx); s[j]=p; sum+=p; }
    float inv=(n>0)? 1.0f/sum:0.f;
    float o[32];
    #pragma unroll
    for (int d=0;d<32;d++) o[d]=0.f;
    for (int j=0;j<INST_MAX;j++){
      float a=s[j]*inv;
      #pragma unroll
      for (int d4=0;d4<8;d4++){
        float4 vv=*reinterpret_cast<const float4*>(&vh[j*128+h*32+d4*4]);
        o[d4*4]+=a*vv.x; o[d4*4+1]+=a*vv.y; o[d4*4+2]+=a*vv.z; o[d4*4+3]+=a*vv.w;
      }
    }
    __syncthreads();
    #pragma unroll
    for (int d8=0;d8<8;d8++){
      float4 v; v.x=o[d8*4]; v.y=o[d8*4+1]; v.z=o[d8*4+2]; v.w=o[d8*4+3];
      *reinterpret_cast<float4*>(&ot[tokl][h*32+d8*4])=v;
    }
  }
  __syncthreads();
  int tx=t&15, ty=t>>4, ty4=ty*4, ecol=tx*8;
  float acc[4][8];
  #pragma unroll
  for (int i=0;i<4;i++)
    #pragma unroll
    for (int j=0;j<8;j++) acc[i][j]=0.f;
  for (int k=0;k<128;k+=4){
    float4 xv0=*reinterpret_cast<const float4*>(&ot[ty4+0][k]);
    float4 xv1=*reinterpret_cast<const float4*>(&ot[ty4+1][k]);
    float4 xv2=*reinterpret_cast<const float4*>(&ot[ty4+2][k]);
    float4 xv3=*reinterpret_cast<const float4*>(&ot[ty4+3][k]);
    #pragma unroll
    for (int jj=0;jj<8;jj++){
      float4 w=*reinterpret_cast<const float4*>(Wo+(size_t)(ecol+jj)*128+k);
      acc[0][jj]+=xv0.x*w.x+xv0.y*w.y+xv0.z*w.z+xv0.w*w.w;
      acc[1][jj]+=xv1.x*w.x+xv1.y*w.y+xv1.z*w.z+xv1.w*w.w;
      acc[2][jj]+=xv2.x*w.x+xv2.y*w.y+xv2.z*w.z+xv2.w*w.w;
      acc[3][jj]+=xv3.x*w.x+xv3.y*w.y+xv3.z*w.z+xv3.w*w.w;
    }
  }
  float4 boa=*reinterpret_cast<const float4*>(bo+ecol);
  float4 bob=*reinterpret_cast<const float4*>(bo+ecol+4);
  float4 ga=*reinterpret_cast<const float4*>(g+ecol);
  float4 gb=*reinterpret_cast<const float4*>(g+ecol+4);
  float4 ba=*reinterpret_cast<const float4*>(bb+ecol);
  float4 bbv=*reinterpret_cast<const float4*>(bb+ecol+4);
  float pe[8][3];
  #pragma unroll
  for (int jj=0;jj<8;jj++){
    pe[jj][0]=pwl[(ecol+jj)*3]; pe[jj][1]=pwl[(ecol+jj)*3+1]; pe[jj][2]=pwl[(ecol+jj)*3+2];
  }
  #pragma unroll
  for (int i=0;i<4;i++){
    int r=r0+ty4+i;
    float4 se1=*reinterpret_cast<const float4*>(SE+(size_t)r*128+ecol);
    float4 se2=*reinterpret_cast<const float4*>(SE+(size_t)r*128+ecol+4);
    float X=px[ty4+i], Y=py[ty4+i], Z=pz[ty4+i];
    acc[i][0]+=boa.x+se1.x+X*pe[0][0]+Y*pe[0][1]+Z*pe[0][2];
    acc[i][1]+=boa.y+se1.y+X*pe[1][0]+Y*pe[1][1]+Z*pe[1][2];
    acc[i][2]+=boa.z+se1.z+X*pe[2][0]+Y*pe[2][1]+Z*pe[2][2];
    acc[i][3]+=boa.w+se1.w+X*pe[3][0]+Y*pe[3][1]+Z*pe[3][2];
    acc[i][4]+=bob.x+se2.x+X*pe[4][0]+Y*pe[4][1]+Z*pe[4][2];
    acc[i][5]+=bob.y+se2.y+X*pe[5][0]+Y*pe[5][1]+Z*pe[5][2];
    acc[i][6]+=bob.z+se2.z+X*pe[6][0]+Y*pe[6][1]+Z*pe[6][2];
    acc[i][7]+=bob.w+se2.w+X*pe[7][0]+Y*pe[7][1]+Z*pe[7][2];
    float s1=0.f;
    #pragma unroll
    for (int jj=0;jj<8;jj++) s1+=acc[i][jj];
    s1+=__shfl_xor(s1,1); s1+=__shfl_xor(s1,2); s1+=__shfl_xor(s1,4); s1+=__shfl_xor(s1,8);
    float mu=s1*(1.f/128.f);
    float vv=0.f;
    #pragma unroll
    for (int jj=0;jj<8;jj++){ float d=acc[i][jj]-mu; acc[i][jj]=d; vv+=d*d; }
    vv+=__shfl_xor(vv,1); vv+=__shfl_xor(vv,2); vv+=__shfl_xor(vv,4); vv+=__shfl_xor(vv,8);
    float rsv=rsqrtf(vv*(1.f/128.f)+1e-5f);
    if (r<nf){
      float4 o1,o2;
      o1.x=acc[i][0]*rsv*ga.x+ba.x; o1.y=acc[i][1]*rsv*ga.y+ba.y;
      o1.z=acc[i][2]*rsv*ga.z+ba.z; o1.w=acc[i][3]*rsv*ga.w+ba.w;
      o2.x=acc[i][4]*rsv*gb.x+bbv.x; o2.y=acc[i][5]*rsv*gb.y+bbv.y;
      o2.z=acc[i][6]*rsv*gb.z+bbv.z; o2.w=acc[i][7]*rsv*gb.w+bbv.w;
      *reinterpret_cast<float4*>(A2+(size_t)r*128+ecol)=o1;
      *reinterpret_cast<float4*>(A2+(size_t)r*128+ecol+4)=o2;
    }
  }
}

__global__ void k_transpose(const float* in, float* outp, int R, int C){
  __shared__ float tile[32][33];
  int bx=blockIdx.x*32, by=blockIdx.y*32;
  int tx=threadIdx.x, ty=threadIdx.y;
  for (int k=0;k<4;k++){
    int r=by+ty+k*8, c=bx+tx;
    if (r<R && c<C) tile[ty+k*8][tx]=in[(size_t)r*C+c];
  }
  __syncthreads();
  for (int k=0;k<4;k++){
    int cc=bx+ty+k*8, rr=by+tx;
    if (rr<R && cc<C) outp[(size_t)cc*R+rr]=tile[tx][ty+k*8];
  }
}

// Fused FFN (v1, measured 357us): pinned.
__global__ __launch_bounds__(256) void kFFN(const float* X_, float* SEo, const float* W1T, const float* W2T,
    const float* b1, const float* b2, const float* g, const float* bb, float* ws){
  int* iw=(int*)ws;
  int nf=iw[S_NF];
  int r0=blockIdx.x*64;
  if (r0>=nf) return;
  __shared__ float Xs[64][132];
  __shared__ float Hs[64][68];
  int t=threadIdx.x;
  int tx=t&15, ty=t>>4;
  int ty4=ty*4;
  int ecol=tx*8;
  for (int idx=t; idx<64*32; idx+=256){
    int rl=idx>>5, e4=idx&31;
    int r=r0+rl;
    float4 v = (r<nf)? reinterpret_cast<const float4*>(X_+(size_t)r*128)[e4]
                     : make_float4(0.f,0.f,0.f,0.f);
    *reinterpret_cast<float4*>(&Xs[rl][e4*4]) = v;
  }
  __syncthreads();
  float yacc[4][8];
  #pragma unroll
  for (int i=0;i<4;i++)
    #pragma unroll
    for (int j=0;j<8;j++) yacc[i][j]=0.f;
  for (int dc=0; dc<512; dc+=64){
    int dcol = dc + tx*4;
    float acc[4][4];
    #pragma unroll
    for (int i=0;i<4;i++)
      #pragma unroll
      for (int j=0;j<4;j++) acc[i][j]=0.f;
    for (int k=0;k<128;k+=4){
      float4 w0=*reinterpret_cast<const float4*>(W1T+(size_t)(k+0)*512+dcol);
      float4 w1=*reinterpret_cast<const float4*>(W1T+(size_t)(k+1)*512+dcol);
      float4 w2=*reinterpret_cast<const float4*>(W1T+(size_t)(k+2)*512+dcol);
      float4 w3=*reinterpret_cast<const float4*>(W1T+(size_t)(k+3)*512+dcol);
      #pragma unroll
      for (int i=0;i<4;i++){
        float4 xv=*reinterpret_cast<const float4*>(&Xs[ty4+i][k]);
        acc[i][0]+=xv.x*w0.x; acc[i][1]+=xv.x*w0.y; acc[i][2]+=xv.x*w0.z; acc[i][3]+=xv.x*w0.w;
        acc[i][0]+=xv.y*w1.x; acc[i][1]+=xv.y*w1.y; acc[i][2]+=xv.y*w1.z; acc[i][3]+=xv.y*w1.w;
        acc[i][0]+=xv.z*w2.x; acc[i][1]+=xv.z*w2.y; acc[i][2]+=xv.z*w2.z; acc[i][3]+=xv.z*w2.w;
        acc[i][0]+=xv.w*w3.x; acc[i][1]+=xv.w*w3.y; acc[i][2]+=xv.w*w3.z; acc[i][3]+=xv.w*w3.w;
      }
    }
    float4 b1v=*reinterpret_cast<const float4*>(b1+dcol);
    #pragma unroll
    for (int i=0;i<4;i++){
      float4 h;
      h.x=fmaxf(acc[i][0]+b1v.x,0.f);
      h.y=fmaxf(acc[i][1]+b1v.y,0.f);
      h.z=fmaxf(acc[i][2]+b1v.z,0.f);
      h.w=fmaxf(acc[i][3]+b1v.w,0.f);
      *reinterpret_cast<float4*>(&Hs[ty4+i][tx*4])=h;
    }
    __syncthreads();
    for (int d=0; d<64; d+=4){
      float4 ha0=*reinterpret_cast<const float4*>(&Hs[ty4+0][d]);
      float4 ha1=*reinterpret_cast<const float4*>(&Hs[ty4+1][d]);
      float4 ha2=*reinterpret_cast<const float4*>(&Hs[ty4+2][d]);
      float4 ha3=*reinterpret_cast<const float4*>(&Hs[ty4+3][d]);
      #pragma unroll
      for (int kk=0;kk<4;kk++){
        const float* wrow=W2T+(size_t)(dc+d+kk)*128+ecol;
        float4 wa=*reinterpret_cast<const float4*>(wrow);
        float4 wb=*reinterpret_cast<const float4*>(wrow+4);
        float h0 = (kk==0)?ha0.x:(kk==1)?ha0.y:(kk==2)?ha0.z:ha0.w;
        float h1 = (kk==0)?ha1.x:(kk==1)?ha1.y:(kk==2)?ha1.z:ha1.w;
        float h2 = (kk==0)?ha2.x:(kk==1)?ha2.y:(kk==2)?ha2.z:ha2.w;
        float h3 = (kk==0)?ha3.x:(kk==1)?ha3.y:(kk==2)?ha3.z:ha3.w;
        yacc[0][0]+=h0*wa.x; yacc[0][1]+=h0*wa.y; yacc[0][2]+=h0*wa.z; yacc[0][3]+=h0*wa.w;
        yacc[0][4]+=h0*wb.x; yacc[0][5]+=h0*wb.y; yacc[0][6]+=h0*wb.z; yacc[0][7]+=h0*wb.w;
        yacc[1][0]+=h1*wa.x; yacc[1][1]+=h1*wa.y; yacc[1][2]+=h1*wa.z; yacc[1][3]+=h1*wa.w;
        yacc[1][4]+=h1*wb.x; yacc[1][5]+=h1*wb.y; yacc[1][6]+=h1*wb.z; yacc[1][7]+=h1*wb.w;
        yacc[2][0]+=h2*wa.x; yacc[2][1]+=h2*wa.y; yacc[2][2]+=h2*wa.z; yacc[2][3]+=h2*wa.w;
        yacc[2][4]+=h2*wb.x; yacc[2][5]+=h2*wb.y; yacc[2][6]+=h2*wb.z; yacc[2][7]+=h2*wb.w;
        yacc[3][0]+=h3*wa.x; yacc[3][1]+=h3*wa.y; yacc[3][2]+=h3*wa.z; yacc[3][3]+=h3*wa.w;
        yacc[3][4]+=h3*wb.x; yacc[3][5]+=h3*wb.y; yacc[3][6]+=h3*wb.z; yacc[3][7]+=h3*wb.w;
      }
    }
    __syncthreads();
  }
  float4 b2a=*reinterpret_cast<const float4*>(b2+ecol);
  float4 b2b=*reinterpret_cast<const float4*>(b2+ecol+4);
  #pragma unroll
  for (int i=0;i<4;i++){
    float4 xa=*reinterpret_cast<const float4*>(&Xs[ty4+i][ecol]);
    float4 xb=*reinterpret_cast<const float4*>(&Xs[ty4+i][ecol+4]);
    xa.x+=yacc[i][0]+b2a.x; xa.y+=yacc[i][1]+b2a.y; xa.z+=yacc[i][2]+b2a.z; xa.w+=yacc[i][3]+b2a.w;
    xb.x+=yacc[i][4]+b2b.x; xb.y+=yacc[i][5]+b2b.y; xb.z+=yacc[i][6]+b2b.z; xb.w+=yacc[i][7]+b2b.w;
    *reinterpret_cast<float4*>(&Xs[ty4+i][ecol])=xa;
    *reinterpret_cast<float4*>(&Xs[ty4+i][ecol+4])=xb;
  }
  __syncthreads();
  int w=t>>6, lane=t&63;
  for (int rl=w; rl<64; rl+=4){
    int r=r0+rl;
    float v0=Xs[rl][lane], v1=Xs[rl][64+lane];
    float s=v0+v1;
    for (int o=32;o>0;o>>=1) s+=__shfl_xor(s,o);
    float mu=s*(1.f/128.f);
    float d0=v0-mu, d1=v1-mu;
    float vv=d0*d0+d1*d1;
    for (int o=32;o>0;o>>=1) vv+=__shfl_xor(vv,o);
    float rsv=rsqrtf(vv*(1.f/128.f)+1e-5f);
    if (r<nf){
      SEo[r*128+lane]=d0*rsv*g[lane]+bb[lane];
      SEo[r*128+64+lane]=d1*rsv*g[64+lane]+bb[64+lane];
    }
  }
}

// k_out v2: rows padded to 132 for ds_read_b128; thread = (q, o-slot of 5);
// cw reads are wave-uniform broadcasts.
__global__ __launch_bounds__(256) void k_out(const float* SE, const float* sew, const float* x3d,
    const float* convw, const float* convb, const int* invr, float* out, float* ws){
  (void)ws;
  __shared__ float rows[64][132];
  __shared__ float cw[20*128];
  __shared__ float cb[20];
  __shared__ int rkl[64];
  int t=threadIdx.x;
  int q0=blockIdx.x*64;
  for (int idx=t; idx<20*128; idx+=256) cw[idx]=convw[idx];
  if (t<20) cb[t]=convb[t];
  if (t<64) rkl[t]=invr[q0+t];
  __syncthreads();
  for (int idx=t; idx<64*32; idx+=256){
    int v=idx>>5, e4=(idx&31)*4;
    int rk=rkl[v];
    float4 val = (rk>=0)? *reinterpret_cast<const float4*>(SE+(size_t)rk*128+e4)
                        : *reinterpret_cast<const float4*>(sew+(size_t)(q0+v)*128+e4);
    *reinterpret_cast<float4*>(&rows[v][e4])=val;
  }
  __syncthreads();
  for (int idx=t; idx<128*64; idx+=256){
    int c=idx>>6, v=idx&63;
    if (rkl[v]<0) rows[v][c]+=x3d[(size_t)c*NQ+q0+v];
  }
  __syncthreads();
  int v=t&63, slot=t>>6;
  float acc[5]={0.f,0.f,0.f,0.f,0.f};
  for (int c=0;c<128;c+=4){
    float4 rv=*reinterpret_cast<const float4*>(&rows[v][c]);
    #pragma unroll
    for (int oo=0;oo<5;oo++){
      float4 cv=*reinterpret_cast<const float4*>(&cw[(slot*5+oo)*128+c]);
      acc[oo]+=rv.x*cv.x+rv.y*cv.y+rv.z*cv.z+rv.w*cv.w;
    }
  }
  #pragma unroll
  for (int oo=0;oo<5;oo++){
    int o=slot*5+oo;
    out[(size_t)o*NQ+q0+v]=acc[oo]+cb[o];
  }
}

extern "C" void kernel_launch(void* const* d_in, const int* in_sizes, int n_in,
                              void* d_out, int out_size, void* d_ws, size_t ws_size,
                              hipStream_t stream){
  (void)in_sizes; (void)n_in; (void)out_size; (void)ws_size;
  const float* queries  = (const float*)d_in[0];
  const float* plogits  = (const float*)d_in[1];
  const float* pmasks   = (const float*)d_in[2];
  const float* x3d      = (const float*)d_in[3];
  const float* depth    = (const float*)d_in[4];
  const float* Kmat     = (const float*)d_in[5];
  const float* Emat     = (const float*)d_in[6];
  const float* vorigin  = (const float*)d_in[7];
  const int*   fov      = (const int*)d_in[8];
  const float* sew      = (const float*)d_in[9];
  const float* instposw = (const float*)d_in[10];
  const float* posw     = (const float*)d_in[11];
  const float* convw    = (const float*)d_in[12];
  const float* convb    = (const float*)d_in[13];
  const float* AW       = (const float*)d_in[14];
  const float* AB       = (const float*)d_in[15];
  const float* LG       = (const float*)d_in[16];
  const float* LB       = (const float*)d_in[17];
  const float* F1W      = (const float*)d_in[18];
  const float* F1B      = (const float*)d_in[19];
  const float* F2W      = (const float*)d_in[20];
  const float* F2B      = (const float*)d_in[21];
  float* out = (float*)d_out;
  char* wsb = (char*)d_ws;
  float* fws = (float*)d_ws;
  int* fidx = (int*)(wsb + OFF_FIDX);
  int* invr = (int*)(wsb + OFF_INV);
  float* SE = (float*)(wsb + OFF_SE);
  float* A1 = (float*)(wsb + OFF_A1);
  float* A2 = (float*)(wsb + OFF_A2);
  float* SC = (float*)(wsb + OFF_SC);
  float* W1Ta[2] = { (float*)(wsb + OFF_W1T),              (float*)(wsb + OFF_W1T + 512*1024) };
  float* W2Ta[2] = { (float*)(wsb + OFF_W1T + 256*1024),   (float*)(wsb + OFF_W1T + 768*1024) };

  auto aw  = [&](int i,int br,int m){ return AW + (size_t)(((i*2+br)*4+m))*128*128; };
  auto ab  = [&](int i,int br,int m){ return AB + (size_t)(((i*2+br)*4+m))*128; };
  auto lng = [&](int i,int br,int wch){ return LG + (size_t)(((i*2+br)*2+wch))*128; };
  auto lnb = [&](int i,int br,int wch){ return LB + (size_t)(((i*2+br)*2+wch))*128; };
  auto f1w = [&](int i,int br){ return F1W + (size_t)(i*2+br)*512*128; };
  auto f1b = [&](int i,int br){ return F1B + (size_t)(i*2+br)*512; };
  auto f2w = [&](int i,int br){ return F2W + (size_t)(i*2+br)*128*512; };
  auto f2b = [&](int i,int br){ return F2B + (size_t)(i*2+br)*128; };

  const int NB64 = NF_MAX/64;   // 1152

  k_init<<<1,256,0,stream>>>(Kmat,Emat,fws);
  k_score<<<1,320,0,stream>>>(plogits,fws);
  k_winner<<<NPIX/256,256,0,stream>>>(pmasks,depth,fws);
  k_sel<<<1,256,0,stream>>>(queries,instposw,posw,fws);
  k_fov_count<<<256,256,0,stream>>>(fov,fws);
  k_fov_scan<<<1,64,0,stream>>>(fws);
  k_fov_scatter<<<256,256,0,stream>>>(fov,fws);
  k_se_build<<<NB64,256,0,stream>>>(sew,x3d,fidx,SE,fws);
  // hoisted FFN weight transposes (both layers)
  for (int i=0;i<2;i++){
    k_transpose<<<dim3(4,16),dim3(32,8),0,stream>>>(f1w(i,1),W1Ta[i],512,128);
    k_transpose<<<dim3(16,4),dim3(32,8),0,stream>>>(f2w(i,1),W2Ta[i],128,512);
  }

  for (int i=0;i<2;i++){
    // ---- instance-side layer (queries = instances, keys/vals = scene) ----
    kA_prep<<<IH_MAX,256,0,stream>>>(aw(i,0,0),ab(i,0,0),aw(i,0,1),ab(i,0,1),fws);
    kS1<<<NB64,256,0,stream>>>(SE,SC,posw,vorigin,fidx,fws);
    kS2S3<<<IH_MAX,256,0,stream>>>(SC,fws);
    kS4<<<256,256,0,stream>>>(SC,SE,fws);
    kA_tail<<<INST_MAX,256,0,stream>>>(
      aw(i,0,2),ab(i,0,2), aw(i,0,3),ab(i,0,3), lng(i,0,0),lnb(i,0,0),
      f1w(i,0),f1b(i,0), f2w(i,0),f2b(i,0), lng(i,0,1),lnb(i,0,1),
      aw(i,1,1),ab(i,1,1), aw(i,1,2),ab(i,1,2), fws);
    // ---- scene-side layer (queries = scene, keys/vals = instances) ----
    kQ<<<NB64,256,0,stream>>>(A1,aw(i,1,0),ab(i,1,0),SE,fidx,posw,vorigin,fws);
    kAttnOLN<<<NB64,256,0,stream>>>(A1,A2,aw(i,1,3),ab(i,1,3),lng(i,1,0),lnb(i,1,0),SE,fidx,posw,vorigin,fws);
    kFFN<<<NB64,256,0,stream>>>(A2,SE,W1Ta[i],W2Ta[i],f1b(i,1),f2b(i,1),lng(i,1,1),lnb(i,1,1),fws);
  }
  k_out<<<NQ/64,256,0,stream>>>(SE,sew,x3d,convw,convb,invr,out,fws);
}